// Round 1
// baseline (309.514 us; speedup 1.0000x reference)
//
#include <hip/hip_runtime.h>
#include <math.h>

typedef __attribute__((ext_vector_type(8))) short bf8v;
typedef __attribute__((ext_vector_type(4))) float f4v;

__device__ __forceinline__ float bf2f(unsigned short u) {
  union { unsigned int i; float f; } c; c.i = ((unsigned int)u) << 16; return c.f;
}
__device__ __forceinline__ unsigned short f2bf(float f) {
  union { float f; unsigned int i; } c; c.f = f;
  return (unsigned short)((c.i + 0x7fffu + ((c.i >> 16) & 1u)) >> 16);
}

// ---------------- LayerNorm: x (16384 rows x 512) fp32 -> xn bf16 ----------------
__global__ __launch_bounds__(64) void ln_kernel(const float* __restrict__ x,
    const float* __restrict__ gamma, const float* __restrict__ beta,
    unsigned short* __restrict__ xn) {
  const int row = blockIdx.x;
  const int lane = threadIdx.x;
  const float4* xr = (const float4*)(x + (size_t)row * 512);
  const float4 v0 = xr[lane * 2], v1 = xr[lane * 2 + 1];
  float s  = v0.x + v0.y + v0.z + v0.w + v1.x + v1.y + v1.z + v1.w;
  float sq = v0.x*v0.x + v0.y*v0.y + v0.z*v0.z + v0.w*v0.w
           + v1.x*v1.x + v1.y*v1.y + v1.z*v1.z + v1.w*v1.w;
  #pragma unroll
  for (int off = 32; off >= 1; off >>= 1) {
    s  += __shfl_xor(s, off);
    sq += __shfl_xor(sq, off);
  }
  const float mu   = s * (1.f / 512.f);
  const float var  = sq * (1.f / 512.f) - mu * mu;
  const float rstd = rsqrtf(var + 1e-5f);
  const float4* gp = (const float4*)gamma + lane * 2;
  const float4* bp = (const float4*)beta  + lane * 2;
  const float4 g0 = gp[0], g1 = gp[1], bb0 = bp[0], bb1 = bp[1];
  const float o0 = (v0.x - mu) * rstd * g0.x + bb0.x;
  const float o1 = (v0.y - mu) * rstd * g0.y + bb0.y;
  const float o2 = (v0.z - mu) * rstd * g0.z + bb0.z;
  const float o3 = (v0.w - mu) * rstd * g0.w + bb0.w;
  const float o4 = (v1.x - mu) * rstd * g1.x + bb1.x;
  const float o5 = (v1.y - mu) * rstd * g1.y + bb1.y;
  const float o6 = (v1.z - mu) * rstd * g1.z + bb1.z;
  const float o7 = (v1.w - mu) * rstd * g1.w + bb1.w;
  uint4 pk;
  pk.x = (unsigned)f2bf(o0) | ((unsigned)f2bf(o1) << 16);
  pk.y = (unsigned)f2bf(o2) | ((unsigned)f2bf(o3) << 16);
  pk.z = (unsigned)f2bf(o4) | ((unsigned)f2bf(o5) << 16);
  pk.w = (unsigned)f2bf(o6) | ((unsigned)f2bf(o7) << 16);
  ((uint4*)(xn + (size_t)row * 512))[lane] = pk;
}

// ---------------- FiLM: film[b,j] = silu(emb[b]) . W_film[j] + b_film[j] ----------------
__global__ __launch_bounds__(256) void film_kernel(const float* __restrict__ emb,
    const float* __restrict__ Wf, const float* __restrict__ bfm,
    float* __restrict__ film) {
  const int gw = blockIdx.x * 4 + (threadIdx.x >> 6);   // 0..8191
  const int lane = threadIdx.x & 63;
  const int b = gw >> 10, j = gw & 1023;
  const float4* ep = (const float4*)(emb + (size_t)b * 512) + lane * 2;
  const float4* wp = (const float4*)(Wf + (size_t)j * 512) + lane * 2;
  float acc = 0.f;
  #pragma unroll
  for (int i = 0; i < 2; i++) {
    const float4 e = ep[i], w = wp[i];
    acc += (e.x / (1.f + expf(-e.x))) * w.x;
    acc += (e.y / (1.f + expf(-e.y))) * w.y;
    acc += (e.z / (1.f + expf(-e.z))) * w.z;
    acc += (e.w / (1.f + expf(-e.w))) * w.w;
  }
  #pragma unroll
  for (int off = 32; off >= 1; off >>= 1) acc += __shfl_xor(acc, off);
  if (lane == 0) film[(size_t)b * 1024 + j] = acc + bfm[j];
}

// ---------------- W_out fp32 -> bf16 ----------------
__global__ __launch_bounds__(256) void wcvt_kernel(const float* __restrict__ W,
    unsigned short* __restrict__ Wb) {
  const int i = blockIdx.x * 256 + threadIdx.x;   // x4 floats
  const float4 v = ((const float4*)W)[i];
  uint2 pk;
  pk.x = (unsigned)f2bf(v.x) | ((unsigned)f2bf(v.y) << 16);
  pk.y = (unsigned)f2bf(v.z) | ((unsigned)f2bf(v.w) << 16);
  ((uint2*)Wb)[i] = pk;
}

// ---------------- S4D scan: wave per (b,d); lane = state n ----------------
// y2t[b,d,l] = ((conv + D_skip*xn) * (1+scale) + shift) in bf16, transposed layout
__global__ __launch_bounds__(256) void scan_kernel(
    const unsigned short* __restrict__ xn,
    const float* __restrict__ A_real, const float* __restrict__ A_imag,
    const float* __restrict__ Cc, const float* __restrict__ log_dt,
    const float* __restrict__ B_ssm, const float* __restrict__ D_skip,
    const float* __restrict__ film, unsigned short* __restrict__ y2t) {
  __shared__ float pbuf[4][64 * 33];   // stride 33: all accesses 2 lanes/bank (free)
  const int w = threadIdx.x >> 6, lane = threadIdx.x & 63;
  const int wid = blockIdx.x * 4 + w;
  const int b = wid >> 9, d = wid & 511;
  const int dn = d * 64 + lane;
  const float dt  = expf(log_dt[d]);
  const float er  = expf(dt * A_real[dn]);
  const float th  = dt * A_imag[dn];
  const float wre = er * cosf(th), wim = er * sinf(th);
  const float bs  = B_ssm[dn];
  const float c0  = Cc[dn * 2 + 0] * bs * dt;
  const float c1  = Cc[dn * 2 + 1] * bs * dt;
  const float dsk = D_skip[d];
  const float scl = 1.f + film[(size_t)b * 1024 + d];
  const float shf = film[(size_t)b * 1024 + 512 + d];
  float sre = 0.f, sim = 0.f;
  const unsigned short* xp = xn + ((size_t)b * 2048) * 512 + d;
  unsigned short* yp = y2t + ((size_t)b * 512 + d) * 2048;
  float* pb = pbuf[w];
  const int t = lane >> 1, h = lane & 1;
  for (int t0 = 0; t0 < 2048; t0 += 32) {
    const unsigned short* xq = xp + (size_t)t0 * 512;
    #pragma unroll
    for (int tt = 0; tt < 32; tt++) {
      const float xv = bf2f(xq[tt * 512]);
      const float nre = fmaf(wre, sre, fmaf(-wim, sim, xv));
      const float nim = fmaf(wre, sim, wim * sre);
      sre = nre; sim = nim;
      pb[lane * 33 + tt] = fmaf(c0, sre, -(c1 * sim));
    }
    __builtin_amdgcn_wave_barrier();   // wave-synchronous LDS exchange; HW DS is in-order per wave
    float acc = 0.f;
    const int rb = h * 32;
    #pragma unroll
    for (int j = 0; j < 32; j++) acc += pb[(rb + j) * 33 + t];
    acc += __shfl_xor(acc, 1);
    if (h == 0) {
      const float xv = bf2f(xq[t * 512]);
      float y = fmaf(dsk, xv, acc);
      y = fmaf(y, scl, shf);
      yp[t0 + t] = f2bf(y);
    }
    __builtin_amdgcn_wave_barrier();
  }
}

// ---------------- out_proj + GLU + residual: bf16 MFMA ----------------
// block: 64 m-rows x (64 'a' cols + 64 'g' cols); wave owns 16-row strip
__global__ __launch_bounds__(256) void gemm_kernel(
    const unsigned short* __restrict__ y2t, const unsigned short* __restrict__ Wb,
    const float* __restrict__ bo, const float* __restrict__ x,
    float* __restrict__ out) {
  __shared__ __align__(16) unsigned short Al[64 * 48];
  __shared__ __align__(16) unsigned short Bl[128 * 48];
  const int mt = blockIdx.x, ct = blockIdx.y;
  const int tid = threadIdx.x;
  const int wv = tid >> 6, lane = tid & 63;
  const int n15 = lane & 15, quad = lane >> 4;
  const int m0 = mt * 64;
  const int b = m0 >> 11, l0 = m0 & 2047;
  f4v acc[2][4];
  #pragma unroll
  for (int hh = 0; hh < 2; hh++)
    #pragma unroll
    for (int t4 = 0; t4 < 4; t4++) acc[hh][t4] = (f4v){0.f, 0.f, 0.f, 0.f};

  const int kr  = tid >> 3;        // 0..31 (k row of A tile)
  const int m8  = (tid & 7) * 8;   // m offset of 8-elem run
  const int cc0 = tid >> 2;        // 0..63 (c row of B tile)
  const int ks  = (tid & 3) * 8;   // k offset

  for (int kk = 0; kk < 16; kk++) {
    { // stage A: y2t is m-contiguous -> transpose into Al[m][k]
      const unsigned short* src =
          y2t + ((size_t)(b * 512 + kk * 32 + kr)) * 2048 + l0 + m8;
      const uint4 v = *(const uint4*)src;
      const int ab = m8 * 48 + kr;
      Al[ab + 0 * 48] = (unsigned short)(v.x & 0xffffu);
      Al[ab + 1 * 48] = (unsigned short)(v.x >> 16);
      Al[ab + 2 * 48] = (unsigned short)(v.y & 0xffffu);
      Al[ab + 3 * 48] = (unsigned short)(v.y >> 16);
      Al[ab + 4 * 48] = (unsigned short)(v.z & 0xffffu);
      Al[ab + 5 * 48] = (unsigned short)(v.z >> 16);
      Al[ab + 6 * 48] = (unsigned short)(v.w & 0xffffu);
      Al[ab + 7 * 48] = (unsigned short)(v.w >> 16);
    }
    #pragma unroll
    for (int r = 0; r < 2; r++) { // stage B: Wb rows are k-contiguous, direct
      const int cc = cc0 + r * 64;
      const int cg = (cc < 64) ? (ct * 64 + cc) : (512 + ct * 64 + (cc - 64));
      const uint4 v = *(const uint4*)(Wb + (size_t)cg * 512 + kk * 32 + ks);
      *(uint4*)&Bl[cc * 48 + ks] = v;
    }
    __syncthreads();
    const bf8v a = *(const bf8v*)&Al[(wv * 16 + n15) * 48 + quad * 8];
    #pragma unroll
    for (int hh = 0; hh < 2; hh++)
      #pragma unroll
      for (int t4 = 0; t4 < 4; t4++) {
        const bf8v bb = *(const bf8v*)&Bl[(hh * 64 + t4 * 16 + n15) * 48 + quad * 8];
        acc[hh][t4] = __builtin_amdgcn_mfma_f32_16x16x32_bf16(a, bb, acc[hh][t4], 0, 0, 0);
      }
    __syncthreads();
  }
  const int mrow = m0 + wv * 16 + quad * 4;
  #pragma unroll
  for (int t4 = 0; t4 < 4; t4++) {
    const int c = ct * 64 + t4 * 16 + n15;
    const float ba = bo[c], bg = bo[512 + c];
    #pragma unroll
    for (int i = 0; i < 4; i++) {
      const size_t off = (size_t)(mrow + i) * 512 + c;
      const float av = acc[0][t4][i] + ba;
      const float gv = acc[1][t4][i] + bg;
      out[off] = x[off] + av * (1.f / (1.f + __expf(-gv)));
    }
  }
}

extern "C" void kernel_launch(void* const* d_in, const int* in_sizes, int n_in,
                              void* d_out, int out_size, void* d_ws, size_t ws_size,
                              hipStream_t stream) {
  const float* x      = (const float*)d_in[0];
  const float* emb    = (const float*)d_in[1];
  const float* A_real = (const float*)d_in[2];
  const float* A_imag = (const float*)d_in[3];
  const float* C      = (const float*)d_in[4];
  const float* log_dt = (const float*)d_in[5];
  const float* B_ssm  = (const float*)d_in[6];
  const float* D_skip = (const float*)d_in[7];
  const float* gamma  = (const float*)d_in[8];
  const float* beta   = (const float*)d_in[9];
  const float* W_out  = (const float*)d_in[10];
  const float* b_out  = (const float*)d_in[11];
  const float* W_film = (const float*)d_in[12];
  const float* b_film = (const float*)d_in[13];
  float* out = (float*)d_out;

  char* ws = (char*)d_ws;
  float* film         = (float*)ws;                                   // 32 KB
  unsigned short* xn  = (unsigned short*)(ws + (1u << 15));           // 16 MB bf16 (B,L,d)
  unsigned short* y2t = (unsigned short*)(ws + (1u << 15) + (1u << 24)); // 16 MB bf16 (B,d,L)
  unsigned short* Wb  = (unsigned short*)(ws + (1u << 15) + (1u << 25)); // 1 MB bf16

  film_kernel<<<dim3(2048), dim3(256), 0, stream>>>(emb, W_film, b_film, film);
  ln_kernel<<<dim3(16384), dim3(64), 0, stream>>>(x, gamma, beta, xn);
  wcvt_kernel<<<dim3(512), dim3(256), 0, stream>>>(W_out, Wb);
  scan_kernel<<<dim3(1024), dim3(256), 0, stream>>>(xn, A_real, A_imag, C, log_dt,
                                                    B_ssm, D_skip, film, y2t);
  gemm_kernel<<<dim3(256, 8), dim3(256), 0, stream>>>(y2t, Wb, b_out, x, out);
}

// Round 2
// 215.242 us; speedup vs baseline: 1.4380x; 1.4380x over previous
//
#include <hip/hip_runtime.h>
#include <math.h>

typedef __attribute__((ext_vector_type(8))) short bf8v;
typedef __attribute__((ext_vector_type(4))) float f4v;

union BF8 { bf8v v; unsigned short e[8]; };

__device__ __forceinline__ float bf2f(unsigned short u) {
  union { unsigned int i; float f; } c; c.i = ((unsigned int)u) << 16; return c.f;
}
__device__ __forceinline__ unsigned short f2bf(float f) {
  union { float f; unsigned int i; } c; c.f = f;
  return (unsigned short)((c.i + 0x7fffu + ((c.i >> 16) & 1u)) >> 16);
}

// ---------------- LayerNorm: x (16384 rows x 512) fp32 -> xn bf16 (b*l, d) ----------------
__global__ __launch_bounds__(64) void ln_kernel(const float* __restrict__ x,
    const float* __restrict__ gamma, const float* __restrict__ beta,
    unsigned short* __restrict__ xn) {
  const int row = blockIdx.x;
  const int lane = threadIdx.x;
  const float4* xr = (const float4*)(x + (size_t)row * 512);
  const float4 v0 = xr[lane * 2], v1 = xr[lane * 2 + 1];
  float s  = v0.x + v0.y + v0.z + v0.w + v1.x + v1.y + v1.z + v1.w;
  float sq = v0.x*v0.x + v0.y*v0.y + v0.z*v0.z + v0.w*v0.w
           + v1.x*v1.x + v1.y*v1.y + v1.z*v1.z + v1.w*v1.w;
  #pragma unroll
  for (int off = 32; off >= 1; off >>= 1) {
    s  += __shfl_xor(s, off);
    sq += __shfl_xor(sq, off);
  }
  const float mu   = s * (1.f / 512.f);
  const float var  = sq * (1.f / 512.f) - mu * mu;
  const float rstd = rsqrtf(var + 1e-5f);
  const float4* gp = (const float4*)gamma + lane * 2;
  const float4* bp = (const float4*)beta  + lane * 2;
  const float4 g0 = gp[0], g1 = gp[1], bb0 = bp[0], bb1 = bp[1];
  const float o0 = (v0.x - mu) * rstd * g0.x + bb0.x;
  const float o1 = (v0.y - mu) * rstd * g0.y + bb0.y;
  const float o2 = (v0.z - mu) * rstd * g0.z + bb0.z;
  const float o3 = (v0.w - mu) * rstd * g0.w + bb0.w;
  const float o4 = (v1.x - mu) * rstd * g1.x + bb1.x;
  const float o5 = (v1.y - mu) * rstd * g1.y + bb1.y;
  const float o6 = (v1.z - mu) * rstd * g1.z + bb1.z;
  const float o7 = (v1.w - mu) * rstd * g1.w + bb1.w;
  uint4 pk;
  pk.x = (unsigned)f2bf(o0) | ((unsigned)f2bf(o1) << 16);
  pk.y = (unsigned)f2bf(o2) | ((unsigned)f2bf(o3) << 16);
  pk.z = (unsigned)f2bf(o4) | ((unsigned)f2bf(o5) << 16);
  pk.w = (unsigned)f2bf(o6) | ((unsigned)f2bf(o7) << 16);
  ((uint4*)(xn + (size_t)row * 512))[lane] = pk;
}

// ---------------- FiLM ----------------
__global__ __launch_bounds__(256) void film_kernel(const float* __restrict__ emb,
    const float* __restrict__ Wf, const float* __restrict__ bfm,
    float* __restrict__ film) {
  const int gw = blockIdx.x * 4 + (threadIdx.x >> 6);
  const int lane = threadIdx.x & 63;
  const int b = gw >> 10, j = gw & 1023;
  const float4* ep = (const float4*)(emb + (size_t)b * 512) + lane * 2;
  const float4* wp = (const float4*)(Wf + (size_t)j * 512) + lane * 2;
  float acc = 0.f;
  #pragma unroll
  for (int i = 0; i < 2; i++) {
    const float4 e = ep[i], w = wp[i];
    acc += (e.x / (1.f + __expf(-e.x))) * w.x;
    acc += (e.y / (1.f + __expf(-e.y))) * w.y;
    acc += (e.z / (1.f + __expf(-e.z))) * w.z;
    acc += (e.w / (1.f + __expf(-e.w))) * w.w;
  }
  #pragma unroll
  for (int off = 32; off >= 1; off >>= 1) acc += __shfl_xor(acc, off);
  if (lane == 0) film[(size_t)b * 1024 + j] = acc + bfm[j];
}

// ---------------- W_out fp32 -> bf16 ----------------
__global__ __launch_bounds__(256) void wcvt_kernel(const float* __restrict__ W,
    unsigned short* __restrict__ Wb) {
  const int i = blockIdx.x * 256 + threadIdx.x;
  const float4 v = ((const float4*)W)[i];
  uint2 pk;
  pk.x = (unsigned)f2bf(v.x) | ((unsigned)f2bf(v.y) << 16);
  pk.y = (unsigned)f2bf(v.z) | ((unsigned)f2bf(v.w) << 16);
  ((uint2*)Wb)[i] = pk;
}

// ---------------- generic u16 transpose: in[R][C] -> out[C][R], 64x64 tiles ----------------
// LDS col-group XOR swizzle keeps both write and read phases <=2-way bank aliased.
__global__ __launch_bounds__(256) void tr_kernel(const unsigned short* __restrict__ in,
    unsigned short* __restrict__ out, int R, int C) {
  __shared__ __align__(16) unsigned short t[64 * 72];
  const int c0 = blockIdx.x * 64, r0 = blockIdx.y * 64;
  const int tid = threadIdx.x;
  #pragma unroll
  for (int i = 0; i < 2; i++) {
    const int idx = tid + i * 256;          // 0..511
    const int r = idx >> 3, q = idx & 7;    // row, col-group
    const uint4 v = *(const uint4*)(in + (size_t)(r0 + r) * C + c0 + q * 8);
    *(uint4*)&t[r * 72 + ((q ^ (r >> 3)) * 8)] = v;
  }
  __syncthreads();
  #pragma unroll
  for (int i = 0; i < 2; i++) {
    const int idx = tid + i * 256;
    const int c = idx >> 3, g = idx & 7;    // out row c, 8-row group g
    union { unsigned short s[8]; uint4 u; } pk;
    #pragma unroll
    for (int j = 0; j < 8; j++)
      pk.s[j] = t[(g * 8 + j) * 72 + (((c >> 3) ^ g) * 8) + (c & 7)];
    *(uint4*)(out + (size_t)(c0 + c) * R + r0 + g * 8) = pk.u;
  }
}

// ---------------- K table: Kt[d][tau] = Re(sum_n cdt_n w_n^tau) (+D_skip at tau=0) ----------------
__global__ __launch_bounds__(256) void ktab_kernel(const float* __restrict__ A_real,
    const float* __restrict__ A_imag, const float* __restrict__ Cc,
    const float* __restrict__ log_dt, const float* __restrict__ B_ssm,
    const float* __restrict__ D_skip, float* __restrict__ Kt) {
  const int d = blockIdx.x * 4 + (threadIdx.x >> 6);
  const int n = threadIdx.x & 63;
  const int dn = d * 64 + n;
  const float dt = __expf(log_dt[d]);
  const float er = __expf(dt * A_real[dn]);
  float sw, cw; __sincosf(dt * A_imag[dn], &sw, &cw);
  const float wre = er * cw, wim = er * sw;
  const float bs = B_ssm[dn] * dt;
  float pre = Cc[dn * 2] * bs, pim = Cc[dn * 2 + 1] * bs;   // cdt * w^0
  const float dsk = D_skip[d];
  for (int tau = 0; tau < 64; tau++) {
    float r = pre;
    #pragma unroll
    for (int off = 32; off >= 1; off >>= 1) r += __shfl_xor(r, off);
    if (n == 0) Kt[d * 64 + tau] = (tau == 0) ? (r + dsk) : r;
    const float nre = pre * wre - pim * wim;
    const float nim = pre * wim + pim * wre;
    pre = nre; pim = nim;
  }
}

// ---------------- chunked SSM, one block per d ----------------
// j = b*32 + chunk (256 cols), t/s in [0,64). All per-d matrices generated in-register.
// Phase1: E[n,j] = P @ X.  Phase2: 32-step carry prefix -> I (bf16 in LDS).
// Phase3: Y = T @ X + Mre @ Ire^T + (-Mim) @ Iim^T; FiLM epilogue; y2[d][j*64+t].
__global__ __launch_bounds__(256, 1) void ssm_kernel(
    const unsigned short* __restrict__ xT,   // [512][16384] = [d][j*64+s]
    const float* __restrict__ A_real, const float* __restrict__ A_imag,
    const float* __restrict__ Cc, const float* __restrict__ log_dt,
    const float* __restrict__ B_ssm, const float* __restrict__ Kt,
    const float* __restrict__ film, unsigned short* __restrict__ y2) {
  extern __shared__ char smem[];
  unsigned int*   Eb  = (unsigned int*)smem;                  // [64][258] packed bf16 re|im
  unsigned short* Ibr = (unsigned short*)(smem + 64 * 258 * 4); // [256][72]
  unsigned short* Ibi = Ibr + 256 * 72;

  const int d = blockIdx.x;
  const int tid = threadIdx.x;
  const int wv = tid >> 6, lane = tid & 63;
  const int n15 = lane & 15, quad = lane >> 4;
  const int j0 = wv * 64;
  const float dt = __expf(log_dt[d]);

  // X fragments (B-operand: rows j, k = s) — reused in phases 1 and 3
  bf8v Xf[4][2];
  #pragma unroll
  for (int ct = 0; ct < 4; ct++)
    #pragma unroll
    for (int kq = 0; kq < 2; kq++) {
      const int j = j0 + ct * 16 + n15;
      Xf[ct][kq] = *(const bf8v*)(xT + (size_t)d * 16384 + j * 64 + kq * 32 + quad * 8);
    }

  // ---- Phase 1: E = P @ X
  {
    f4v Er[4][4], Ei[4][4];
    #pragma unroll
    for (int a = 0; a < 4; a++)
      #pragma unroll
      for (int b2 = 0; b2 < 4; b2++) { Er[a][b2] = (f4v){0,0,0,0}; Ei[a][b2] = (f4v){0,0,0,0}; }
    #pragma unroll
    for (int mt = 0; mt < 4; mt++) {
      const int n = mt * 16 + n15;
      const float ar = dt * A_real[d * 64 + n], ai = dt * A_imag[d * 64 + n];
      #pragma unroll
      for (int kq = 0; kq < 2; kq++) {
        BF8 pr, pi;
        #pragma unroll
        for (int j = 0; j < 8; j++) {
          const float k = (float)(63 - (kq * 32 + quad * 8 + j));
          const float ex = __expf(ar * k);
          float sn, cs; __sincosf(ai * k, &sn, &cs);
          pr.e[j] = f2bf(ex * cs);
          pi.e[j] = f2bf(ex * sn);
        }
        #pragma unroll
        for (int ct = 0; ct < 4; ct++) {
          Er[mt][ct] = __builtin_amdgcn_mfma_f32_16x16x32_bf16(pr.v, Xf[ct][kq], Er[mt][ct], 0, 0, 0);
          Ei[mt][ct] = __builtin_amdgcn_mfma_f32_16x16x32_bf16(pi.v, Xf[ct][kq], Ei[mt][ct], 0, 0, 0);
        }
      }
    }
    #pragma unroll
    for (int mt = 0; mt < 4; mt++)
      #pragma unroll
      for (int ct = 0; ct < 4; ct++)
        #pragma unroll
        for (int i = 0; i < 4; i++) {
          const int row = mt * 16 + quad * 4 + i;
          const int col = j0 + ct * 16 + n15;
          Eb[row * 258 + col] =
              (unsigned)f2bf(Er[mt][ct][i]) | ((unsigned)f2bf(Ei[mt][ct][i]) << 16);
        }
  }
  __syncthreads();

  // ---- Phase 2: carry prefix. thread (n = tid&63, bp = tid>>6) handles b = bp, bp+4
  {
    const int n = tid & 63, bp = tid >> 6;
    const int dn = d * 64 + n;
    const float ex = __expf(dt * A_real[dn] * 64.f);
    float sn, cs; __sincosf(dt * A_imag[dn] * 64.f, &sn, &cs);
    const float w64re = ex * cs, w64im = ex * sn;
    #pragma unroll
    for (int half = 0; half < 2; half++) {
      const int b = bp + half * 4;
      float str = 0.f, sti = 0.f;
      for (int c = 0; c < 32; c++) {
        const int j = b * 32 + c;
        Ibr[j * 72 + n] = f2bf(str);          // I entering chunk c
        Ibi[j * 72 + n] = f2bf(sti);
        const unsigned e = Eb[n * 258 + j];
        const float er2 = bf2f((unsigned short)(e & 0xffffu));
        const float ei2 = bf2f((unsigned short)(e >> 16));
        const float nr = er2 + w64re * str - w64im * sti;
        const float ni = ei2 + w64re * sti + w64im * str;
        str = nr; sti = ni;
      }
    }
  }
  __syncthreads();

  // ---- Phase 3: Y = T @ X + corr
  f4v Y[4][4];
  #pragma unroll
  for (int a = 0; a < 4; a++)
    #pragma unroll
    for (int b2 = 0; b2 < 4; b2++) Y[a][b2] = (f4v){0,0,0,0};

  #pragma unroll
  for (int mt = 0; mt < 4; mt++) {
    const int t = mt * 16 + n15;
    #pragma unroll
    for (int kq = 0; kq < 2; kq++) {
      BF8 tf;
      #pragma unroll
      for (int j = 0; j < 8; j++) {
        const int s = kq * 32 + quad * 8 + j;
        tf.e[j] = (s <= t) ? f2bf(Kt[d * 64 + (t - s)]) : (unsigned short)0;
      }
      #pragma unroll
      for (int ct = 0; ct < 4; ct++)
        Y[mt][ct] = __builtin_amdgcn_mfma_f32_16x16x32_bf16(tf.v, Xf[ct][kq], Y[mt][ct], 0, 0, 0);
    }
  }

  #pragma unroll
  for (int kq = 0; kq < 2; kq++) {
    float arj[8], aij[8], c0j[8], c1j[8];
    #pragma unroll
    for (int j = 0; j < 8; j++) {
      const int dn = d * 64 + kq * 32 + quad * 8 + j;
      arj[j] = dt * A_real[dn];
      aij[j] = dt * A_imag[dn];
      const float bs = B_ssm[dn] * dt;
      c0j[j] = Cc[dn * 2] * bs;
      c1j[j] = Cc[dn * 2 + 1] * bs;
    }
    bf8v irf[4], iif[4];
    #pragma unroll
    for (int ct = 0; ct < 4; ct++) {
      const int j = j0 + ct * 16 + n15;
      irf[ct] = *(const bf8v*)&Ibr[j * 72 + kq * 32 + quad * 8];
      iif[ct] = *(const bf8v*)&Ibi[j * 72 + kq * 32 + quad * 8];
    }
    #pragma unroll
    for (int mt = 0; mt < 4; mt++) {
      const int t = mt * 16 + n15;
      BF8 mr, mi;
      #pragma unroll
      for (int j = 0; j < 8; j++) {
        const float k = (float)(t + 1);
        const float ex = __expf(arj[j] * k);
        float sn, cs; __sincosf(aij[j] * k, &sn, &cs);
        mr.e[j] = f2bf(ex * (c0j[j] * cs - c1j[j] * sn));
        mi.e[j] = f2bf(-ex * (c0j[j] * sn + c1j[j] * cs));   // pre-negated Mim
      }
      #pragma unroll
      for (int ct = 0; ct < 4; ct++) {
        Y[mt][ct] = __builtin_amdgcn_mfma_f32_16x16x32_bf16(mr.v, irf[ct], Y[mt][ct], 0, 0, 0);
        Y[mt][ct] = __builtin_amdgcn_mfma_f32_16x16x32_bf16(mi.v, iif[ct], Y[mt][ct], 0, 0, 0);
      }
    }
  }

  // ---- epilogue: FiLM + store y2[d][j*64 + t] bf16
  #pragma unroll
  for (int ct = 0; ct < 4; ct++) {
    const int j = j0 + ct * 16 + n15;
    const int b = j >> 5;
    const float scl = 1.f + film[b * 1024 + d];
    const float shf = film[b * 1024 + 512 + d];
    #pragma unroll
    for (int mt = 0; mt < 4; mt++) {
      union { unsigned short s[4]; uint2 u; } pk;
      #pragma unroll
      for (int i = 0; i < 4; i++)
        pk.s[i] = f2bf(fmaf(Y[mt][ct][i], scl, shf));
      *(uint2*)(y2 + (size_t)d * 16384 + j * 64 + mt * 16 + quad * 4) = pk.u;
    }
  }
}

// ---------------- out_proj + GLU + residual: bf16 MFMA, A staged b128 from y2n (b*l, d) ----------------
__global__ __launch_bounds__(256) void gemm_kernel(
    const unsigned short* __restrict__ y2n, const unsigned short* __restrict__ Wb,
    const float* __restrict__ bo, const float* __restrict__ x,
    float* __restrict__ out) {
  __shared__ __align__(16) unsigned short Al[64 * 48];
  __shared__ __align__(16) unsigned short Bl[128 * 48];
  const int m0 = blockIdx.x * 64, ct = blockIdx.y;
  const int tid = threadIdx.x;
  const int wv = tid >> 6, lane = tid & 63;
  const int n15 = lane & 15, quad = lane >> 4;
  f4v acc[2][4];
  #pragma unroll
  for (int hh = 0; hh < 2; hh++)
    #pragma unroll
    for (int t4 = 0; t4 < 4; t4++) acc[hh][t4] = (f4v){0.f, 0.f, 0.f, 0.f};

  const int ar  = tid >> 2;        // A row 0..63
  const int ak  = (tid & 3) * 8;   // A k-offset
  const int cc0 = tid >> 2;        // B row 0..63 (and +64)
  const int ks  = (tid & 3) * 8;

  for (int kk = 0; kk < 16; kk++) {
    *(uint4*)&Al[ar * 48 + ak] =
        *(const uint4*)(y2n + (size_t)(m0 + ar) * 512 + kk * 32 + ak);
    #pragma unroll
    for (int r = 0; r < 2; r++) {
      const int cc = cc0 + r * 64;
      const int cg = (cc < 64) ? (ct * 64 + cc) : (512 + ct * 64 + (cc - 64));
      *(uint4*)&Bl[cc * 48 + ks] = *(const uint4*)(Wb + (size_t)cg * 512 + kk * 32 + ks);
    }
    __syncthreads();
    const bf8v a = *(const bf8v*)&Al[(wv * 16 + n15) * 48 + quad * 8];
    #pragma unroll
    for (int hh = 0; hh < 2; hh++)
      #pragma unroll
      for (int t4 = 0; t4 < 4; t4++) {
        const bf8v bb = *(const bf8v*)&Bl[(hh * 64 + t4 * 16 + n15) * 48 + quad * 8];
        acc[hh][t4] = __builtin_amdgcn_mfma_f32_16x16x32_bf16(a, bb, acc[hh][t4], 0, 0, 0);
      }
    __syncthreads();
  }
  const int mrow = m0 + wv * 16 + quad * 4;
  #pragma unroll
  for (int t4 = 0; t4 < 4; t4++) {
    const int c = ct * 64 + t4 * 16 + n15;
    const float ba = bo[c], bg = bo[512 + c];
    #pragma unroll
    for (int i = 0; i < 4; i++) {
      const size_t off = (size_t)(mrow + i) * 512 + c;
      const float av = acc[0][t4][i] + ba;
      const float gv = acc[1][t4][i] + bg;
      out[off] = x[off] + av * (1.f / (1.f + __expf(-gv)));
    }
  }
}

extern "C" void kernel_launch(void* const* d_in, const int* in_sizes, int n_in,
                              void* d_out, int out_size, void* d_ws, size_t ws_size,
                              hipStream_t stream) {
  const float* x      = (const float*)d_in[0];
  const float* emb    = (const float*)d_in[1];
  const float* A_real = (const float*)d_in[2];
  const float* A_imag = (const float*)d_in[3];
  const float* C      = (const float*)d_in[4];
  const float* log_dt = (const float*)d_in[5];
  const float* B_ssm  = (const float*)d_in[6];
  const float* D_skip = (const float*)d_in[7];
  const float* gamma  = (const float*)d_in[8];
  const float* beta   = (const float*)d_in[9];
  const float* W_out  = (const float*)d_in[10];
  const float* b_out  = (const float*)d_in[11];
  const float* W_film = (const float*)d_in[12];
  const float* b_film = (const float*)d_in[13];
  float* out = (float*)d_out;

  char* ws = (char*)d_ws;
  float*          film = (float*)ws;                                  // 32 KB
  unsigned short* xn   = (unsigned short*)(ws + 32768);               // 16 MB (b*l, d)
  unsigned short* xT   = (unsigned short*)(ws + 32768 + 16777216);    // 16 MB (d, b*l)
  float*          Kt   = (float*)(ws + 32768 + 2 * 16777216);         // 128 KB
  unsigned short* Wb   = (unsigned short*)(ws + 32768 + 2 * 16777216 + 131072); // 1 MB
  unsigned short* y2   = xn;   // xn dead after tr1 -> reuse for y2 (d, b*l)
  unsigned short* y2n  = xT;   // xT dead after ssm -> reuse for y2n (b*l, d)

  film_kernel<<<dim3(2048), dim3(256), 0, stream>>>(emb, W_film, b_film, film);
  ln_kernel<<<dim3(16384), dim3(64), 0, stream>>>(x, gamma, beta, xn);
  wcvt_kernel<<<dim3(512), dim3(256), 0, stream>>>(W_out, Wb);
  ktab_kernel<<<dim3(128), dim3(256), 0, stream>>>(A_real, A_imag, C, log_dt, B_ssm, D_skip, Kt);
  tr_kernel<<<dim3(8, 256), dim3(256), 0, stream>>>(xn, xT, 16384, 512);
  ssm_kernel<<<dim3(512), dim3(256), 139776, stream>>>(xT, A_real, A_imag, C, log_dt,
                                                       B_ssm, Kt, film, y2);
  tr_kernel<<<dim3(256, 8), dim3(256), 0, stream>>>(y2, y2n, 512, 16384);
  gemm_kernel<<<dim3(256, 8), dim3(256), 0, stream>>>(y2n, Wb, b_out, x, out);
}

// Round 3
// 205.307 us; speedup vs baseline: 1.5076x; 1.0484x over previous
//
#include <hip/hip_runtime.h>
#include <math.h>

typedef __attribute__((ext_vector_type(8))) short bf8v;
typedef __attribute__((ext_vector_type(4))) float f4v;

union BF8 { bf8v v; unsigned short e[8]; };

__device__ __forceinline__ float bf2f(unsigned short u) {
  union { unsigned int i; float f; } c; c.i = ((unsigned int)u) << 16; return c.f;
}
__device__ __forceinline__ unsigned short f2bf(float f) {
  union { float f; unsigned int i; } c; c.f = f;
  return (unsigned short)((c.i + 0x7fffu + ((c.i >> 16) & 1u)) >> 16);
}
// global -> LDS direct DMA, 16B per lane; lds must be wave-uniform (dest = lds + lane*16)
__device__ __forceinline__ void gld16(const unsigned short* g, unsigned short* l) {
  __builtin_amdgcn_global_load_lds(
      (const __attribute__((address_space(1))) unsigned int*)g,
      (__attribute__((address_space(3))) unsigned int*)l, 16, 0, 0);
}

// ---------------- LayerNorm: x (16384 x 512) fp32 -> xn bf16 (b*l, d) ----------------
__global__ __launch_bounds__(64) void ln_kernel(const float* __restrict__ x,
    const float* __restrict__ gamma, const float* __restrict__ beta,
    unsigned short* __restrict__ xn) {
  const int row = blockIdx.x;
  const int lane = threadIdx.x;
  const float4* xr = (const float4*)(x + (size_t)row * 512);
  const float4 v0 = xr[lane * 2], v1 = xr[lane * 2 + 1];
  float s  = v0.x + v0.y + v0.z + v0.w + v1.x + v1.y + v1.z + v1.w;
  float sq = v0.x*v0.x + v0.y*v0.y + v0.z*v0.z + v0.w*v0.w
           + v1.x*v1.x + v1.y*v1.y + v1.z*v1.z + v1.w*v1.w;
  #pragma unroll
  for (int off = 32; off >= 1; off >>= 1) {
    s  += __shfl_xor(s, off);
    sq += __shfl_xor(sq, off);
  }
  const float mu   = s * (1.f / 512.f);
  const float var  = sq * (1.f / 512.f) - mu * mu;
  const float rstd = rsqrtf(var + 1e-5f);
  const float4* gp = (const float4*)gamma + lane * 2;
  const float4* bp = (const float4*)beta  + lane * 2;
  const float4 g0 = gp[0], g1 = gp[1], bb0 = bp[0], bb1 = bp[1];
  const float o0 = (v0.x - mu) * rstd * g0.x + bb0.x;
  const float o1 = (v0.y - mu) * rstd * g0.y + bb0.y;
  const float o2 = (v0.z - mu) * rstd * g0.z + bb0.z;
  const float o3 = (v0.w - mu) * rstd * g0.w + bb0.w;
  const float o4 = (v1.x - mu) * rstd * g1.x + bb1.x;
  const float o5 = (v1.y - mu) * rstd * g1.y + bb1.y;
  const float o6 = (v1.z - mu) * rstd * g1.z + bb1.z;
  const float o7 = (v1.w - mu) * rstd * g1.w + bb1.w;
  uint4 pk;
  pk.x = (unsigned)f2bf(o0) | ((unsigned)f2bf(o1) << 16);
  pk.y = (unsigned)f2bf(o2) | ((unsigned)f2bf(o3) << 16);
  pk.z = (unsigned)f2bf(o4) | ((unsigned)f2bf(o5) << 16);
  pk.w = (unsigned)f2bf(o6) | ((unsigned)f2bf(o7) << 16);
  ((uint4*)(xn + (size_t)row * 512))[lane] = pk;
}

// ---------------- FiLM ----------------
__global__ __launch_bounds__(256) void film_kernel(const float* __restrict__ emb,
    const float* __restrict__ Wf, const float* __restrict__ bfm,
    float* __restrict__ film) {
  const int gw = blockIdx.x * 4 + (threadIdx.x >> 6);
  const int lane = threadIdx.x & 63;
  const int b = gw >> 10, j = gw & 1023;
  const float4* ep = (const float4*)(emb + (size_t)b * 512) + lane * 2;
  const float4* wp = (const float4*)(Wf + (size_t)j * 512) + lane * 2;
  float acc = 0.f;
  #pragma unroll
  for (int i = 0; i < 2; i++) {
    const float4 e = ep[i], w = wp[i];
    acc += (e.x / (1.f + __expf(-e.x))) * w.x;
    acc += (e.y / (1.f + __expf(-e.y))) * w.y;
    acc += (e.z / (1.f + __expf(-e.z))) * w.z;
    acc += (e.w / (1.f + __expf(-e.w))) * w.w;
  }
  #pragma unroll
  for (int off = 32; off >= 1; off >>= 1) acc += __shfl_xor(acc, off);
  if (lane == 0) film[(size_t)b * 1024 + j] = acc + bfm[j];
}

// ---------------- W_out fp32 -> bf16 ----------------
__global__ __launch_bounds__(256) void wcvt_kernel(const float* __restrict__ W,
    unsigned short* __restrict__ Wb) {
  const int i = blockIdx.x * 256 + threadIdx.x;
  const float4 v = ((const float4*)W)[i];
  uint2 pk;
  pk.x = (unsigned)f2bf(v.x) | ((unsigned)f2bf(v.y) << 16);
  pk.y = (unsigned)f2bf(v.z) | ((unsigned)f2bf(v.w) << 16);
  ((uint2*)Wb)[i] = pk;
}

// ---------------- generic u16 transpose: in[R][C] -> out[C][R], 64x64 tiles ----------------
__global__ __launch_bounds__(256) void tr_kernel(const unsigned short* __restrict__ in,
    unsigned short* __restrict__ out, int R, int C) {
  __shared__ __align__(16) unsigned short t[64 * 72];
  const int c0 = blockIdx.x * 64, r0 = blockIdx.y * 64;
  const int tid = threadIdx.x;
  #pragma unroll
  for (int i = 0; i < 2; i++) {
    const int idx = tid + i * 256;
    const int r = idx >> 3, q = idx & 7;
    const uint4 v = *(const uint4*)(in + (size_t)(r0 + r) * C + c0 + q * 8);
    *(uint4*)&t[r * 72 + ((q ^ (r >> 3)) * 8)] = v;
  }
  __syncthreads();
  #pragma unroll
  for (int i = 0; i < 2; i++) {
    const int idx = tid + i * 256;
    const int c = idx >> 3, g = idx & 7;
    union { unsigned short s[8]; uint4 u; } pk;
    #pragma unroll
    for (int j = 0; j < 8; j++)
      pk.s[j] = t[(g * 8 + j) * 72 + (((c >> 3) ^ g) * 8) + (c & 7)];
    *(uint4*)(out + (size_t)(c0 + c) * R + r0 + g * 8) = pk.u;
  }
}

// ---------------- K table: Kt[d][tau] = Re(sum_n cdt_n w_n^tau) (+D_skip at tau=0) ----------------
__global__ __launch_bounds__(256) void ktab_kernel(const float* __restrict__ A_real,
    const float* __restrict__ A_imag, const float* __restrict__ Cc,
    const float* __restrict__ log_dt, const float* __restrict__ B_ssm,
    const float* __restrict__ D_skip, float* __restrict__ Kt) {
  const int d = blockIdx.x * 4 + (threadIdx.x >> 6);
  const int n = threadIdx.x & 63;
  const int dn = d * 64 + n;
  const float dt = __expf(log_dt[d]);
  const float er = __expf(dt * A_real[dn]);
  float sw, cw; __sincosf(dt * A_imag[dn], &sw, &cw);
  const float wre = er * cw, wim = er * sw;
  const float bs = B_ssm[dn] * dt;
  float pre = Cc[dn * 2] * bs, pim = Cc[dn * 2 + 1] * bs;
  const float dsk = D_skip[d];
  for (int tau = 0; tau < 64; tau++) {
    float r = pre;
    #pragma unroll
    for (int off = 32; off >= 1; off >>= 1) r += __shfl_xor(r, off);
    if (n == 0) Kt[d * 64 + tau] = (tau == 0) ? (r + dsk) : r;
    const float nre = pre * wre - pim * wim;
    const float nim = pre * wim + pim * wre;
    pre = nre; pim = nim;
  }
}

// ---------------- table builder: P[n][s], M[t][n], T[t][s], w64 per d ----------------
__global__ __launch_bounds__(256) void tab_kernel(
    const float* __restrict__ A_real, const float* __restrict__ A_imag,
    const float* __restrict__ Cc, const float* __restrict__ log_dt,
    const float* __restrict__ B_ssm, const float* __restrict__ Kt,
    unsigned short* __restrict__ Pre, unsigned short* __restrict__ Pim,
    unsigned short* __restrict__ Mre, unsigned short* __restrict__ Mim,
    unsigned short* __restrict__ Tt, float* __restrict__ W64r, float* __restrict__ W64i) {
  const int d = blockIdx.x;
  const int tid = threadIdx.x;
  const float dt = __expf(log_dt[d]);
  // P[n][s] = w_n^(63-s)
  for (int g = tid; g < 512; g += 256) {
    const int n = g >> 3, s0 = (g & 7) * 8;
    const int dn = d * 64 + n;
    const float ar = dt * A_real[dn], ai = dt * A_imag[dn];
    union { unsigned short s[8]; uint4 u; } pr, pi;
    #pragma unroll
    for (int j = 0; j < 8; j++) {
      const float k = (float)(63 - (s0 + j));
      const float ex = __expf(ar * k);
      float sn, cs; __sincosf(ai * k, &sn, &cs);
      pr.s[j] = f2bf(ex * cs); pi.s[j] = f2bf(ex * sn);
    }
    *(uint4*)(Pre + (size_t)d * 4096 + n * 64 + s0) = pr.u;
    *(uint4*)(Pim + (size_t)d * 4096 + n * 64 + s0) = pi.u;
  }
  // M[t][n]: re = Re(cdt_n w_n^(t+1)), im = -Im(...)
  for (int g = tid; g < 512; g += 256) {
    const int t = g >> 3, n0 = (g & 7) * 8;
    union { unsigned short s[8]; uint4 u; } mr, mi;
    #pragma unroll
    for (int j = 0; j < 8; j++) {
      const int dn = d * 64 + n0 + j;
      const float ar = dt * A_real[dn], ai = dt * A_imag[dn];
      const float bs = B_ssm[dn] * dt;
      const float c0 = Cc[dn * 2] * bs, c1 = Cc[dn * 2 + 1] * bs;
      const float k = (float)(t + 1);
      const float ex = __expf(ar * k);
      float sn, cs; __sincosf(ai * k, &sn, &cs);
      mr.s[j] = f2bf(ex * (c0 * cs - c1 * sn));
      mi.s[j] = f2bf(-ex * (c0 * sn + c1 * cs));
    }
    *(uint4*)(Mre + (size_t)d * 4096 + t * 64 + n0) = mr.u;
    *(uint4*)(Mim + (size_t)d * 4096 + t * 64 + n0) = mi.u;
  }
  // T[t][s] = Kt[t-s] (s<=t)
  for (int g = tid; g < 512; g += 256) {
    const int t = g >> 3, s0 = (g & 7) * 8;
    union { unsigned short s[8]; uint4 u; } tv;
    #pragma unroll
    for (int j = 0; j < 8; j++) {
      const int s = s0 + j;
      tv.s[j] = (s <= t) ? f2bf(Kt[d * 64 + (t - s)]) : (unsigned short)0;
    }
    *(uint4*)(Tt + (size_t)d * 4096 + t * 64 + s0) = tv.u;
  }
  if (tid < 64) {
    const int dn = d * 64 + tid;
    const float ex = __expf(dt * A_real[dn] * 64.f);
    float sn, cs; __sincosf(dt * A_imag[dn] * 64.f, &sn, &cs);
    W64r[d * 64 + tid] = ex * cs;
    W64i[d * 64 + tid] = ex * sn;
  }
}

// ---------------- chunked SSM: block = (d, half of batches); all frags from tables ----------------
__global__ __launch_bounds__(256, 2) void ssm_kernel(
    const unsigned short* __restrict__ xT,
    const unsigned short* __restrict__ Pre, const unsigned short* __restrict__ Pim,
    const unsigned short* __restrict__ Mre, const unsigned short* __restrict__ Mim,
    const unsigned short* __restrict__ Tt,
    const float* __restrict__ W64r, const float* __restrict__ W64i,
    const float* __restrict__ film, unsigned short* __restrict__ y2) {
  extern __shared__ char smem[];
  unsigned int*   Eb  = (unsigned int*)smem;                    // [64][133] packed bf16
  unsigned short* Ibr = (unsigned short*)(smem + 64 * 133 * 4); // [128][72]
  unsigned short* Ibi = Ibr + 128 * 72;

  const int bx = blockIdx.x;
  const int d = bx & 511, h = bx >> 9;
  const int tid = threadIdx.x;
  const int wv = tid >> 6, lane = tid & 63;
  const int n15 = lane & 15, quad = lane >> 4;
  const int j0 = wv * 32;          // local j base (128 j per block)
  const int jg0 = h * 128;         // global j base
  const size_t dtab = (size_t)d * 4096;

  // X fragments (B-operand), reused in phases 1 and 3
  bf8v Xf[2][2];
  #pragma unroll
  for (int ct = 0; ct < 2; ct++)
    #pragma unroll
    for (int kq = 0; kq < 2; kq++) {
      const int j = j0 + ct * 16 + n15;
      Xf[ct][kq] = *(const bf8v*)(xT + (size_t)d * 16384 + (jg0 + j) * 64 + kq * 32 + quad * 8);
    }

  // ---- Phase 1: E = P @ X
  {
    f4v Er[4][2], Ei[4][2];
    #pragma unroll
    for (int a = 0; a < 4; a++)
      #pragma unroll
      for (int b2 = 0; b2 < 2; b2++) { Er[a][b2] = (f4v){0,0,0,0}; Ei[a][b2] = (f4v){0,0,0,0}; }
    #pragma unroll
    for (int mt = 0; mt < 4; mt++)
      #pragma unroll
      for (int kq = 0; kq < 2; kq++) {
        const bf8v pr = *(const bf8v*)(Pre + dtab + (mt * 16 + n15) * 64 + kq * 32 + quad * 8);
        const bf8v pi = *(const bf8v*)(Pim + dtab + (mt * 16 + n15) * 64 + kq * 32 + quad * 8);
        #pragma unroll
        for (int ct = 0; ct < 2; ct++) {
          Er[mt][ct] = __builtin_amdgcn_mfma_f32_16x16x32_bf16(pr, Xf[ct][kq], Er[mt][ct], 0, 0, 0);
          Ei[mt][ct] = __builtin_amdgcn_mfma_f32_16x16x32_bf16(pi, Xf[ct][kq], Ei[mt][ct], 0, 0, 0);
        }
      }
    #pragma unroll
    for (int mt = 0; mt < 4; mt++)
      #pragma unroll
      for (int ct = 0; ct < 2; ct++)
        #pragma unroll
        for (int i = 0; i < 4; i++) {
          const int row = mt * 16 + quad * 4 + i;
          const int col = j0 + ct * 16 + n15;
          Eb[row * 133 + col] =
              (unsigned)f2bf(Er[mt][ct][i]) | ((unsigned)f2bf(Ei[mt][ct][i]) << 16);
        }
  }
  __syncthreads();

  // ---- Phase 2: per-(n, local batch) 32-step carry prefix
  {
    const int n = tid & 63, bp = tid >> 6;
    const float wre = W64r[d * 64 + n], wim = W64i[d * 64 + n];
    unsigned int eb[32];
    #pragma unroll
    for (int c = 0; c < 32; c++) eb[c] = Eb[n * 133 + bp * 32 + c];
    float str = 0.f, sti = 0.f;
    #pragma unroll
    for (int c = 0; c < 32; c++) {
      const int j = bp * 32 + c;
      Ibr[j * 72 + n] = f2bf(str);
      Ibi[j * 72 + n] = f2bf(sti);
      const float er = bf2f((unsigned short)(eb[c] & 0xffffu));
      const float ei = bf2f((unsigned short)(eb[c] >> 16));
      const float nr = er + wre * str - wim * sti;
      const float ni = ei + wre * sti + wim * str;
      str = nr; sti = ni;
    }
  }
  __syncthreads();

  // ---- Phase 3: Y = T @ X + Mre @ Ire^T + Mimn @ Iim^T
  f4v Y[4][2];
  #pragma unroll
  for (int a = 0; a < 4; a++)
    #pragma unroll
    for (int b2 = 0; b2 < 2; b2++) Y[a][b2] = (f4v){0,0,0,0};

  #pragma unroll
  for (int mt = 0; mt < 4; mt++)
    #pragma unroll
    for (int kq = 0; kq < 2; kq++) {
      const bf8v tf = *(const bf8v*)(Tt + dtab + (mt * 16 + n15) * 64 + kq * 32 + quad * 8);
      #pragma unroll
      for (int ct = 0; ct < 2; ct++)
        Y[mt][ct] = __builtin_amdgcn_mfma_f32_16x16x32_bf16(tf, Xf[ct][kq], Y[mt][ct], 0, 0, 0);
    }

  #pragma unroll
  for (int kq = 0; kq < 2; kq++) {
    bf8v irf[2], iif[2];
    #pragma unroll
    for (int ct = 0; ct < 2; ct++) {
      const int j = j0 + ct * 16 + n15;
      irf[ct] = *(const bf8v*)&Ibr[j * 72 + kq * 32 + quad * 8];
      iif[ct] = *(const bf8v*)&Ibi[j * 72 + kq * 32 + quad * 8];
    }
    #pragma unroll
    for (int mt = 0; mt < 4; mt++) {
      const bf8v mr = *(const bf8v*)(Mre + dtab + (mt * 16 + n15) * 64 + kq * 32 + quad * 8);
      const bf8v mi = *(const bf8v*)(Mim + dtab + (mt * 16 + n15) * 64 + kq * 32 + quad * 8);
      #pragma unroll
      for (int ct = 0; ct < 2; ct++) {
        Y[mt][ct] = __builtin_amdgcn_mfma_f32_16x16x32_bf16(mr, irf[ct], Y[mt][ct], 0, 0, 0);
        Y[mt][ct] = __builtin_amdgcn_mfma_f32_16x16x32_bf16(mi, iif[ct], Y[mt][ct], 0, 0, 0);
      }
    }
  }

  // ---- epilogue: FiLM + store y2[d][jglob*64 + t]
  #pragma unroll
  for (int ct = 0; ct < 2; ct++) {
    const int jl = j0 + ct * 16 + n15;
    const int jglob = jg0 + jl;
    const int b = jglob >> 5;
    const float scl = 1.f + film[b * 1024 + d];
    const float shf = film[b * 1024 + 512 + d];
    #pragma unroll
    for (int mt = 0; mt < 4; mt++) {
      union { unsigned short s[4]; uint2 u; } pk;
      #pragma unroll
      for (int i = 0; i < 4; i++)
        pk.s[i] = f2bf(fmaf(Y[mt][ct][i], scl, shf));
      *(uint2*)(y2 + (size_t)d * 16384 + jglob * 64 + mt * 16 + quad * 4) = pk.u;
    }
  }
}

// ---------------- out_proj + GLU + residual: 128x128 tile, global_load_lds staging ----------------
__global__ __launch_bounds__(256, 3) void gemm_kernel(
    const unsigned short* __restrict__ y2n, const unsigned short* __restrict__ Wb,
    const float* __restrict__ bo, const float* __restrict__ x,
    float* __restrict__ out) {
  __shared__ __align__(16) unsigned short Al[128 * 32];
  __shared__ __align__(16) unsigned short Bl[128 * 32];
  const int m0 = blockIdx.x * 128, ct = blockIdx.y;
  const int tid = threadIdx.x;
  const int wv = tid >> 6, lane = tid & 63;
  const int n15 = lane & 15, quad = lane >> 4;
  const int srow = lane >> 2;          // 0..15
  const int sk = (lane & 3) * 8;       // k halves offset within 32

  f4v acc[2][8];
  #pragma unroll
  for (int mi = 0; mi < 2; mi++)
    #pragma unroll
    for (int t4 = 0; t4 < 8; t4++) acc[mi][t4] = (f4v){0.f, 0.f, 0.f, 0.f};

  for (int kk = 0; kk < 16; kk++) {
    #pragma unroll
    for (int i = 0; i < 2; i++) {
      const int row = wv * 32 + i * 16 + srow;
      gld16(y2n + (size_t)(m0 + row) * 512 + kk * 32 + sk, Al + wv * 1024 + i * 512);
      const int c = (row < 64) ? (ct * 64 + row) : (512 + ct * 64 + (row - 64));
      gld16(Wb + (size_t)c * 512 + kk * 32 + sk, Bl + wv * 1024 + i * 512);
    }
    __syncthreads();
    bf8v a0 = *(const bf8v*)&Al[(wv * 32 + n15) * 32 + quad * 8];
    bf8v a1 = *(const bf8v*)&Al[(wv * 32 + 16 + n15) * 32 + quad * 8];
    #pragma unroll
    for (int t4 = 0; t4 < 8; t4++) {
      const bf8v bb = *(const bf8v*)&Bl[(t4 * 16 + n15) * 32 + quad * 8];
      acc[0][t4] = __builtin_amdgcn_mfma_f32_16x16x32_bf16(a0, bb, acc[0][t4], 0, 0, 0);
      acc[1][t4] = __builtin_amdgcn_mfma_f32_16x16x32_bf16(a1, bb, acc[1][t4], 0, 0, 0);
    }
    __syncthreads();
  }
  #pragma unroll
  for (int mi = 0; mi < 2; mi++) {
    const int mrow = m0 + wv * 32 + mi * 16 + quad * 4;
    #pragma unroll
    for (int t4 = 0; t4 < 4; t4++) {
      const int c = ct * 64 + t4 * 16 + n15;
      const float ba = bo[c], bg = bo[512 + c];
      #pragma unroll
      for (int i = 0; i < 4; i++) {
        const size_t off = (size_t)(mrow + i) * 512 + c;
        const float av = acc[mi][t4][i] + ba;
        const float gv = acc[mi][t4 + 4][i] + bg;
        out[off] = x[off] + av * (1.f / (1.f + __expf(-gv)));
      }
    }
  }
}

extern "C" void kernel_launch(void* const* d_in, const int* in_sizes, int n_in,
                              void* d_out, int out_size, void* d_ws, size_t ws_size,
                              hipStream_t stream) {
  const float* x      = (const float*)d_in[0];
  const float* emb    = (const float*)d_in[1];
  const float* A_real = (const float*)d_in[2];
  const float* A_imag = (const float*)d_in[3];
  const float* C      = (const float*)d_in[4];
  const float* log_dt = (const float*)d_in[5];
  const float* B_ssm  = (const float*)d_in[6];
  const float* D_skip = (const float*)d_in[7];
  const float* gamma  = (const float*)d_in[8];
  const float* beta   = (const float*)d_in[9];
  const float* W_out  = (const float*)d_in[10];
  const float* b_out  = (const float*)d_in[11];
  const float* W_film = (const float*)d_in[12];
  const float* b_film = (const float*)d_in[13];
  float* out = (float*)d_out;

  char* ws = (char*)d_ws;
  size_t o = 0;
  float*          film = (float*)(ws + o);          o += 32768;
  unsigned short* xn   = (unsigned short*)(ws + o); o += 16777216;
  unsigned short* xT   = (unsigned short*)(ws + o); o += 16777216;
  float*          Kt   = (float*)(ws + o);          o += 131072;
  unsigned short* Wb   = (unsigned short*)(ws + o); o += 1048576;
  unsigned short* Pre  = (unsigned short*)(ws + o); o += 4194304;
  unsigned short* Pim  = (unsigned short*)(ws + o); o += 4194304;
  unsigned short* Mre  = (unsigned short*)(ws + o); o += 4194304;
  unsigned short* Mim  = (unsigned short*)(ws + o); o += 4194304;
  unsigned short* Tt   = (unsigned short*)(ws + o); o += 4194304;
  float*          W64r = (float*)(ws + o);          o += 131072;
  float*          W64i = (float*)(ws + o);          o += 131072;
  unsigned short* y2   = xn;   // xn dead after tr1
  unsigned short* y2n  = xT;   // xT dead after ssm

  film_kernel<<<dim3(2048), dim3(256), 0, stream>>>(emb, W_film, b_film, film);
  ln_kernel<<<dim3(16384), dim3(64), 0, stream>>>(x, gamma, beta, xn);
  wcvt_kernel<<<dim3(512), dim3(256), 0, stream>>>(W_out, Wb);
  ktab_kernel<<<dim3(128), dim3(256), 0, stream>>>(A_real, A_imag, C, log_dt, B_ssm, D_skip, Kt);
  tab_kernel<<<dim3(512), dim3(256), 0, stream>>>(A_real, A_imag, C, log_dt, B_ssm, Kt,
                                                  Pre, Pim, Mre, Mim, Tt, W64r, W64i);
  tr_kernel<<<dim3(8, 256), dim3(256), 0, stream>>>(xn, xT, 16384, 512);
  ssm_kernel<<<dim3(1024), dim3(256), 70912, stream>>>(xT, Pre, Pim, Mre, Mim, Tt,
                                                       W64r, W64i, film, y2);
  tr_kernel<<<dim3(256, 8), dim3(256), 0, stream>>>(y2, y2n, 512, 16384);
  gemm_kernel<<<dim3(128, 8), dim3(256), 0, stream>>>(y2n, Wb, b_out, x, out);
}

// Round 4
// 196.446 us; speedup vs baseline: 1.5756x; 1.0451x over previous
//
#include <hip/hip_runtime.h>
#include <math.h>

typedef __attribute__((ext_vector_type(8))) short bf8v;
typedef __attribute__((ext_vector_type(4))) float f4v;

union BF8 { bf8v v; unsigned short e[8]; };

__device__ __forceinline__ float bf2f(unsigned short u) {
  union { unsigned int i; float f; } c; c.i = ((unsigned int)u) << 16; return c.f;
}
__device__ __forceinline__ unsigned short f2bf(float f) {
  union { float f; unsigned int i; } c; c.f = f;
  return (unsigned short)((c.i + 0x7fffu + ((c.i >> 16) & 1u)) >> 16);
}
// global -> LDS direct DMA, 16B per lane; LDS dest = wave-uniform base + lane*16
__device__ __forceinline__ void gld16(const unsigned short* g, unsigned short* l) {
  __builtin_amdgcn_global_load_lds(
      (const __attribute__((address_space(1))) unsigned int*)g,
      (__attribute__((address_space(3))) unsigned int*)l, 16, 0, 0);
}

// ---------------- prelude: film (2048 blk) + wcvt (512) + per-d tables (512) ----------------
__global__ __launch_bounds__(256) void prelude_kernel(
    const float* __restrict__ emb, const float* __restrict__ Wf,
    const float* __restrict__ bfm, float* __restrict__ film,
    const float* __restrict__ W, unsigned short* __restrict__ Wb,
    const float* __restrict__ A_real, const float* __restrict__ A_imag,
    const float* __restrict__ Cc, const float* __restrict__ log_dt,
    const float* __restrict__ B_ssm, const float* __restrict__ D_skip,
    unsigned short* __restrict__ Pre, unsigned short* __restrict__ Pim,
    unsigned short* __restrict__ Mre, unsigned short* __restrict__ Mim,
    unsigned short* __restrict__ Tt, float* __restrict__ W64r, float* __restrict__ W64i) {
  __shared__ float Ktl[64];
  const int blk = blockIdx.x;
  const int tid = threadIdx.x;
  if (blk < 2048) {            // ---- FiLM
    const int gw = blk * 4 + (tid >> 6);
    const int lane = tid & 63;
    const int b = gw >> 10, j = gw & 1023;
    const float4* ep = (const float4*)(emb + (size_t)b * 512) + lane * 2;
    const float4* wp = (const float4*)(Wf + (size_t)j * 512) + lane * 2;
    float acc = 0.f;
    #pragma unroll
    for (int i = 0; i < 2; i++) {
      const float4 e = ep[i], w = wp[i];
      acc += (e.x / (1.f + __expf(-e.x))) * w.x;
      acc += (e.y / (1.f + __expf(-e.y))) * w.y;
      acc += (e.z / (1.f + __expf(-e.z))) * w.z;
      acc += (e.w / (1.f + __expf(-e.w))) * w.w;
    }
    #pragma unroll
    for (int off = 32; off >= 1; off >>= 1) acc += __shfl_xor(acc, off);
    if (lane == 0) film[(size_t)b * 1024 + j] = acc + bfm[j];
  } else if (blk < 2560) {     // ---- W_out fp32 -> bf16
    const int i = (blk - 2048) * 256 + tid;
    const float4 v = ((const float4*)W)[i];
    uint2 pk;
    pk.x = (unsigned)f2bf(v.x) | ((unsigned)f2bf(v.y) << 16);
    pk.y = (unsigned)f2bf(v.z) | ((unsigned)f2bf(v.w) << 16);
    ((uint2*)Wb)[i] = pk;
  } else {                     // ---- tables for d
    const int d = blk - 2560;
    const float dt = __expf(log_dt[d]);
    const int wv = tid >> 6, n = tid & 63;
    {  // K[tau] = Re(sum_n cdt_n w_n^tau) (+D_skip at tau=0); wave wv: taus wv*16..+15
      const int dn = d * 64 + n;
      const float ar = dt * A_real[dn], ai = dt * A_imag[dn];
      const float bs = B_ssm[dn] * dt;
      const float c0 = Cc[dn * 2] * bs, c1 = Cc[dn * 2 + 1] * bs;
      #pragma unroll
      for (int i = 0; i < 16; i++) {
        const float tau = (float)(wv * 16 + i);
        const float ex = __expf(ar * tau);
        float sn, cs; __sincosf(ai * tau, &sn, &cs);
        float r = ex * (c0 * cs - c1 * sn);
        #pragma unroll
        for (int off = 32; off >= 1; off >>= 1) r += __shfl_xor(r, off);
        if (n == 0) Ktl[wv * 16 + i] = (wv * 16 + i == 0) ? (r + D_skip[d]) : r;
      }
    }
    __syncthreads();
    // P[n][s] = w_n^(63-s)
    for (int g = tid; g < 512; g += 256) {
      const int nn = g >> 3, s0 = (g & 7) * 8;
      const int dn = d * 64 + nn;
      const float ar = dt * A_real[dn], ai = dt * A_imag[dn];
      union { unsigned short s[8]; uint4 u; } pr, pi;
      #pragma unroll
      for (int j = 0; j < 8; j++) {
        const float k = (float)(63 - (s0 + j));
        const float ex = __expf(ar * k);
        float sn, cs; __sincosf(ai * k, &sn, &cs);
        pr.s[j] = f2bf(ex * cs); pi.s[j] = f2bf(ex * sn);
      }
      *(uint4*)(Pre + (size_t)d * 4096 + nn * 64 + s0) = pr.u;
      *(uint4*)(Pim + (size_t)d * 4096 + nn * 64 + s0) = pi.u;
    }
    // M[t][n]: re = Re(cdt_n w_n^(t+1)), im = -Im(...)
    for (int g = tid; g < 512; g += 256) {
      const int t = g >> 3, n0 = (g & 7) * 8;
      union { unsigned short s[8]; uint4 u; } mr, mi;
      #pragma unroll
      for (int j = 0; j < 8; j++) {
        const int dn = d * 64 + n0 + j;
        const float ar = dt * A_real[dn], ai = dt * A_imag[dn];
        const float bs = B_ssm[dn] * dt;
        const float c0 = Cc[dn * 2] * bs, c1 = Cc[dn * 2 + 1] * bs;
        const float k = (float)(t + 1);
        const float ex = __expf(ar * k);
        float sn, cs; __sincosf(ai * k, &sn, &cs);
        mr.s[j] = f2bf(ex * (c0 * cs - c1 * sn));
        mi.s[j] = f2bf(-ex * (c0 * sn + c1 * cs));
      }
      *(uint4*)(Mre + (size_t)d * 4096 + t * 64 + n0) = mr.u;
      *(uint4*)(Mim + (size_t)d * 4096 + t * 64 + n0) = mi.u;
    }
    // T[t][s] = K[t-s] for s<=t
    for (int g = tid; g < 512; g += 256) {
      const int t = g >> 3, s0 = (g & 7) * 8;
      union { unsigned short s[8]; uint4 u; } tv;
      #pragma unroll
      for (int j = 0; j < 8; j++) {
        const int s = s0 + j;
        tv.s[j] = (s <= t) ? f2bf(Ktl[t - s]) : (unsigned short)0;
      }
      *(uint4*)(Tt + (size_t)d * 4096 + t * 64 + s0) = tv.u;
    }
    if (tid < 64) {
      const int dn = d * 64 + tid;
      const float ex = __expf(dt * A_real[dn] * 64.f);
      float sn, cs; __sincosf(dt * A_imag[dn] * 64.f, &sn, &cs);
      W64r[d * 64 + tid] = ex * cs;
      W64i[d * 64 + tid] = ex * sn;
    }
  }
}

// ---------------- fused LayerNorm + transpose: x (16384 x 512) fp32 -> xT bf16 [d][m] ----------------
__global__ __launch_bounds__(256) void lnt_kernel(const float* __restrict__ x,
    const float* __restrict__ gamma, const float* __restrict__ beta,
    unsigned short* __restrict__ xT) {
  __shared__ __align__(16) unsigned short t[16 * 520];
  const int r0 = blockIdx.x * 16;
  const int tid = threadIdx.x, wv = tid >> 6, lane = tid & 63;
  const float4* gp = (const float4*)gamma + lane * 2;
  const float4* bp = (const float4*)beta  + lane * 2;
  const float4 g0 = gp[0], g1 = gp[1], bb0 = bp[0], bb1 = bp[1];
  #pragma unroll
  for (int i = 0; i < 4; i++) {
    const int r = wv * 4 + i;
    const float4* xr = (const float4*)(x + (size_t)(r0 + r) * 512) + lane * 2;
    const float4 v0 = xr[0], v1 = xr[1];
    float s  = v0.x + v0.y + v0.z + v0.w + v1.x + v1.y + v1.z + v1.w;
    float sq = v0.x*v0.x + v0.y*v0.y + v0.z*v0.z + v0.w*v0.w
             + v1.x*v1.x + v1.y*v1.y + v1.z*v1.z + v1.w*v1.w;
    #pragma unroll
    for (int off = 32; off >= 1; off >>= 1) {
      s  += __shfl_xor(s, off);
      sq += __shfl_xor(sq, off);
    }
    const float mu   = s * (1.f / 512.f);
    const float var  = sq * (1.f / 512.f) - mu * mu;
    const float rstd = rsqrtf(var + 1e-5f);
    uint4 pk;
    pk.x = (unsigned)f2bf((v0.x - mu) * rstd * g0.x + bb0.x)
         | ((unsigned)f2bf((v0.y - mu) * rstd * g0.y + bb0.y) << 16);
    pk.y = (unsigned)f2bf((v0.z - mu) * rstd * g0.z + bb0.z)
         | ((unsigned)f2bf((v0.w - mu) * rstd * g0.w + bb0.w) << 16);
    pk.z = (unsigned)f2bf((v1.x - mu) * rstd * g1.x + bb1.x)
         | ((unsigned)f2bf((v1.y - mu) * rstd * g1.y + bb1.y) << 16);
    pk.w = (unsigned)f2bf((v1.z - mu) * rstd * g1.z + bb1.z)
         | ((unsigned)f2bf((v1.w - mu) * rstd * g1.w + bb1.w) << 16);
    *(uint4*)&t[r * 520 + lane * 8] = pk;
  }
  __syncthreads();
  // transpose-out: thread = col-pair p; gather 16 rows, write xT[2p][r0..+15], xT[2p+1][...]
  const int p = tid;
  union { unsigned short s[8]; uint4 u; } a0, a1, b0, b1;
  #pragma unroll
  for (int r = 0; r < 8; r++) {
    const unsigned v = *(const unsigned*)&t[r * 520 + p * 2];
    a0.s[r] = (unsigned short)(v & 0xffffu);
    b0.s[r] = (unsigned short)(v >> 16);
  }
  #pragma unroll
  for (int r = 0; r < 8; r++) {
    const unsigned v = *(const unsigned*)&t[(r + 8) * 520 + p * 2];
    a1.s[r] = (unsigned short)(v & 0xffffu);
    b1.s[r] = (unsigned short)(v >> 16);
  }
  unsigned short* o0 = xT + (size_t)(2 * p) * 16384 + r0;
  *(uint4*)o0 = a0.u; *(uint4*)(o0 + 8) = a1.u;
  unsigned short* o1 = xT + (size_t)(2 * p + 1) * 16384 + r0;
  *(uint4*)o1 = b0.u; *(uint4*)(o1 + 8) = b1.u;
}

// ---------------- generic u16 transpose: in[R][C] -> out[C][R], 64x64 tiles ----------------
__global__ __launch_bounds__(256) void tr_kernel(const unsigned short* __restrict__ in,
    unsigned short* __restrict__ out, int R, int C) {
  __shared__ __align__(16) unsigned short t[64 * 72];
  const int c0 = blockIdx.x * 64, r0 = blockIdx.y * 64;
  const int tid = threadIdx.x;
  #pragma unroll
  for (int i = 0; i < 2; i++) {
    const int idx = tid + i * 256;
    const int r = idx >> 3, q = idx & 7;
    const uint4 v = *(const uint4*)(in + (size_t)(r0 + r) * C + c0 + q * 8);
    *(uint4*)&t[r * 72 + ((q ^ (r >> 3)) * 8)] = v;
  }
  __syncthreads();
  #pragma unroll
  for (int i = 0; i < 2; i++) {
    const int idx = tid + i * 256;
    const int c = idx >> 3, g = idx & 7;
    union { unsigned short s[8]; uint4 u; } pk;
    #pragma unroll
    for (int j = 0; j < 8; j++)
      pk.s[j] = t[(g * 8 + j) * 72 + (((c >> 3) ^ g) * 8) + (c & 7)];
    *(uint4*)(out + (size_t)(c0 + c) * R + r0 + g * 8) = pk.u;
  }
}

// ---------------- chunked SSM: block = (d, quarter of batches); 4 blocks/CU ----------------
__global__ __launch_bounds__(256, 4) void ssm_kernel(
    const unsigned short* __restrict__ xT,
    const unsigned short* __restrict__ Pre, const unsigned short* __restrict__ Pim,
    const unsigned short* __restrict__ Mre, const unsigned short* __restrict__ Mim,
    const unsigned short* __restrict__ Tt,
    const float* __restrict__ W64r, const float* __restrict__ W64i,
    const float* __restrict__ film, unsigned short* __restrict__ y2) {
  __shared__ unsigned int Eb[64 * 66];          // packed bf16 re|im
  __shared__ unsigned short Ibr[64 * 72], Ibi[64 * 72];

  const int bx = blockIdx.x;
  const int d = bx & 511, h = bx >> 9;
  const int tid = threadIdx.x;
  const int wv = tid >> 6, lane = tid & 63;
  const int n15 = lane & 15, quad = lane >> 4;
  const int j0 = wv * 16;          // local j base (64 j per block)
  const int jg0 = h * 64;          // global j base
  const size_t dtab = (size_t)d * 4096;

  // X fragments (B-operand), reused in phases 1 and 3
  bf8v Xf[2];
  #pragma unroll
  for (int kq = 0; kq < 2; kq++)
    Xf[kq] = *(const bf8v*)(xT + (size_t)d * 16384 + (jg0 + j0 + n15) * 64 + kq * 32 + quad * 8);

  // ---- Phase 1: E = P @ X
  {
    f4v Er[4], Ei[4];
    #pragma unroll
    for (int a = 0; a < 4; a++) { Er[a] = (f4v){0,0,0,0}; Ei[a] = (f4v){0,0,0,0}; }
    #pragma unroll
    for (int mt = 0; mt < 4; mt++)
      #pragma unroll
      for (int kq = 0; kq < 2; kq++) {
        const bf8v pr = *(const bf8v*)(Pre + dtab + (mt * 16 + n15) * 64 + kq * 32 + quad * 8);
        const bf8v pi = *(const bf8v*)(Pim + dtab + (mt * 16 + n15) * 64 + kq * 32 + quad * 8);
        Er[mt] = __builtin_amdgcn_mfma_f32_16x16x32_bf16(pr, Xf[kq], Er[mt], 0, 0, 0);
        Ei[mt] = __builtin_amdgcn_mfma_f32_16x16x32_bf16(pi, Xf[kq], Ei[mt], 0, 0, 0);
      }
    #pragma unroll
    for (int mt = 0; mt < 4; mt++)
      #pragma unroll
      for (int i = 0; i < 4; i++) {
        const int row = mt * 16 + quad * 4 + i;
        Eb[row * 66 + j0 + n15] =
            (unsigned)f2bf(Er[mt][i]) | ((unsigned)f2bf(Ei[mt][i]) << 16);
      }
  }
  __syncthreads();

  // ---- Phase 2: per-(n, batch) 32-step carry prefix (2 batches per block)
  {
    const int n = tid & 63, bp = tid >> 6;
    if (bp < 2) {
      const float wre = W64r[d * 64 + n], wim = W64i[d * 64 + n];
      unsigned int eb[32];
      #pragma unroll
      for (int c = 0; c < 32; c++) eb[c] = Eb[n * 66 + bp * 32 + c];
      float str = 0.f, sti = 0.f;
      #pragma unroll
      for (int c = 0; c < 32; c++) {
        const int j = bp * 32 + c;
        Ibr[j * 72 + n] = f2bf(str);
        Ibi[j * 72 + n] = f2bf(sti);
        const float er = bf2f((unsigned short)(eb[c] & 0xffffu));
        const float ei = bf2f((unsigned short)(eb[c] >> 16));
        const float nr = er + wre * str - wim * sti;
        const float ni = ei + wre * sti + wim * str;
        str = nr; sti = ni;
      }
    }
  }
  __syncthreads();

  // ---- Phase 3: Y = T @ X + Mre @ Ire^T + Mimn @ Iim^T
  f4v Y[4];
  #pragma unroll
  for (int a = 0; a < 4; a++) Y[a] = (f4v){0,0,0,0};

  #pragma unroll
  for (int mt = 0; mt < 4; mt++)
    #pragma unroll
    for (int kq = 0; kq < 2; kq++) {
      const bf8v tf = *(const bf8v*)(Tt + dtab + (mt * 16 + n15) * 64 + kq * 32 + quad * 8);
      Y[mt] = __builtin_amdgcn_mfma_f32_16x16x32_bf16(tf, Xf[kq], Y[mt], 0, 0, 0);
    }

  #pragma unroll
  for (int kq = 0; kq < 2; kq++) {
    const bf8v irf = *(const bf8v*)&Ibr[(j0 + n15) * 72 + kq * 32 + quad * 8];
    const bf8v iif = *(const bf8v*)&Ibi[(j0 + n15) * 72 + kq * 32 + quad * 8];
    #pragma unroll
    for (int mt = 0; mt < 4; mt++) {
      const bf8v mr = *(const bf8v*)(Mre + dtab + (mt * 16 + n15) * 64 + kq * 32 + quad * 8);
      const bf8v mi = *(const bf8v*)(Mim + dtab + (mt * 16 + n15) * 64 + kq * 32 + quad * 8);
      Y[mt] = __builtin_amdgcn_mfma_f32_16x16x32_bf16(mr, irf, Y[mt], 0, 0, 0);
      Y[mt] = __builtin_amdgcn_mfma_f32_16x16x32_bf16(mi, iif, Y[mt], 0, 0, 0);
    }
  }

  // ---- epilogue: FiLM + store y2[d][jglob*64 + t]
  {
    const int jglob = jg0 + j0 + n15;
    const int b = jglob >> 5;
    const float scl = 1.f + film[b * 1024 + d];
    const float shf = film[b * 1024 + 512 + d];
    #pragma unroll
    for (int mt = 0; mt < 4; mt++) {
      union { unsigned short s[4]; uint2 u; } pk;
      #pragma unroll
      for (int i = 0; i < 4; i++)
        pk.s[i] = f2bf(fmaf(Y[mt][i], scl, shf));
      *(uint2*)(y2 + (size_t)d * 16384 + jglob * 64 + mt * 16 + quad * 4) = pk.u;
    }
  }
}

// ---------------- out_proj + GLU + residual: 128x128 tile, BK=64, swizzled LDS ----------------
__global__ __launch_bounds__(256, 3) void gemm_kernel(
    const unsigned short* __restrict__ y2n, const unsigned short* __restrict__ Wb,
    const float* __restrict__ bo, const float* __restrict__ x,
    float* __restrict__ out) {
  __shared__ __align__(16) unsigned short Al[128 * 64];
  __shared__ __align__(16) unsigned short Bl[128 * 64];
  const int m0 = blockIdx.x * 128, ct = blockIdx.y;
  const int tid = threadIdx.x;
  const int wv = tid >> 6, lane = tid & 63;
  const int n15 = lane & 15, quad = lane >> 4;
  const int sr = lane >> 3;                       // 0..7 row-in-group
  const int sk = ((lane & 7) ^ sr) * 8;           // swizzled k-offset (conflict-free reads)

  f4v acc[2][8];
  #pragma unroll
  for (int mi = 0; mi < 2; mi++)
    #pragma unroll
    for (int t4 = 0; t4 < 8; t4++) acc[mi][t4] = (f4v){0.f, 0.f, 0.f, 0.f};

  for (int kk = 0; kk < 8; kk++) {
    #pragma unroll
    for (int c = 0; c < 4; c++) {
      const int row = wv * 32 + c * 8 + sr;
      gld16(y2n + (size_t)(m0 + row) * 512 + kk * 64 + sk, Al + wv * 2048 + c * 512);
      const int cg = (row < 64) ? (ct * 64 + row) : (512 + ct * 64 + (row - 64));
      gld16(Wb + (size_t)cg * 512 + kk * 64 + sk, Bl + wv * 2048 + c * 512);
    }
    __syncthreads();
    #pragma unroll
    for (int kq = 0; kq < 2; kq++) {
      const int r0 = wv * 32 + n15;
      const int r1 = r0 + 16;
      const bf8v a0 = *(const bf8v*)&Al[r0 * 64 + (((kq * 4 + quad) ^ (r0 & 7)) * 8)];
      const bf8v a1 = *(const bf8v*)&Al[r1 * 64 + (((kq * 4 + quad) ^ (r1 & 7)) * 8)];
      #pragma unroll
      for (int t4 = 0; t4 < 8; t4++) {
        const int rb = t4 * 16 + n15;
        const bf8v bb = *(const bf8v*)&Bl[rb * 64 + (((kq * 4 + quad) ^ (rb & 7)) * 8)];
        acc[0][t4] = __builtin_amdgcn_mfma_f32_16x16x32_bf16(a0, bb, acc[0][t4], 0, 0, 0);
        acc[1][t4] = __builtin_amdgcn_mfma_f32_16x16x32_bf16(a1, bb, acc[1][t4], 0, 0, 0);
      }
    }
    __syncthreads();
  }
  #pragma unroll
  for (int mi = 0; mi < 2; mi++) {
    const int mrow = m0 + wv * 32 + mi * 16 + quad * 4;
    #pragma unroll
    for (int t4 = 0; t4 < 4; t4++) {
      const int c = ct * 64 + t4 * 16 + n15;
      const float ba = bo[c], bg = bo[512 + c];
      #pragma unroll
      for (int i = 0; i < 4; i++) {
        const size_t off = (size_t)(mrow + i) * 512 + c;
        const float av = acc[mi][t4][i] + ba;
        const float gv = acc[mi][t4 + 4][i] + bg;
        out[off] = x[off] + av * (1.f / (1.f + __expf(-gv)));
      }
    }
  }
}

extern "C" void kernel_launch(void* const* d_in, const int* in_sizes, int n_in,
                              void* d_out, int out_size, void* d_ws, size_t ws_size,
                              hipStream_t stream) {
  const float* x      = (const float*)d_in[0];
  const float* emb    = (const float*)d_in[1];
  const float* A_real = (const float*)d_in[2];
  const float* A_imag = (const float*)d_in[3];
  const float* C      = (const float*)d_in[4];
  const float* log_dt = (const float*)d_in[5];
  const float* B_ssm  = (const float*)d_in[6];
  const float* D_skip = (const float*)d_in[7];
  const float* gamma  = (const float*)d_in[8];
  const float* beta   = (const float*)d_in[9];
  const float* W_out  = (const float*)d_in[10];
  const float* b_out  = (const float*)d_in[11];
  const float* W_film = (const float*)d_in[12];
  const float* b_film = (const float*)d_in[13];
  float* out = (float*)d_out;

  char* ws = (char*)d_ws;
  size_t o = 0;
  float*          film = (float*)(ws + o);          o += 32768;
  unsigned short* xT   = (unsigned short*)(ws + o); o += 16777216;
  unsigned short* Wb   = (unsigned short*)(ws + o); o += 1048576;
  unsigned short* Pre  = (unsigned short*)(ws + o); o += 4194304;
  unsigned short* Pim  = (unsigned short*)(ws + o); o += 4194304;
  unsigned short* Mre  = (unsigned short*)(ws + o); o += 4194304;
  unsigned short* Mim  = (unsigned short*)(ws + o); o += 4194304;
  unsigned short* Tt   = (unsigned short*)(ws + o); o += 4194304;
  float*          W64r = (float*)(ws + o);          o += 131072;
  float*          W64i = (float*)(ws + o);          o += 131072;
  unsigned short* y2   = (unsigned short*)(ws + o); o += 16777216;   // [d][m]
  unsigned short* y2n  = (unsigned short*)(ws + o); o += 16777216;   // [m][d]

  prelude_kernel<<<dim3(3072), dim3(256), 0, stream>>>(
      emb, W_film, b_film, film, W_out, Wb,
      A_real, A_imag, C, log_dt, B_ssm, D_skip,
      Pre, Pim, Mre, Mim, Tt, W64r, W64i);
  lnt_kernel<<<dim3(1024), dim3(256), 0, stream>>>(x, gamma, beta, xT);
  ssm_kernel<<<dim3(2048), dim3(256), 0, stream>>>(xT, Pre, Pim, Mre, Mim, Tt,
                                                   W64r, W64i, film, y2);
  tr_kernel<<<dim3(256, 8), dim3(256), 0, stream>>>(y2, y2n, 512, 16384);
  gemm_kernel<<<dim3(128, 8), dim3(256), 0, stream>>>(y2n, Wb, b_out, x, out);
}

// Round 5
// 193.328 us; speedup vs baseline: 1.6010x; 1.0161x over previous
//
#include <hip/hip_runtime.h>
#include <math.h>

typedef __attribute__((ext_vector_type(8))) short bf8v;
typedef __attribute__((ext_vector_type(4))) float f4v;

union BF8 { bf8v v; unsigned short e[8]; };

__device__ __forceinline__ float bf2f(unsigned short u) {
  union { unsigned int i; float f; } c; c.i = ((unsigned int)u) << 16; return c.f;
}
__device__ __forceinline__ unsigned short f2bf(float f) {
  union { float f; unsigned int i; } c; c.f = f;
  return (unsigned short)((c.i + 0x7fffu + ((c.i >> 16) & 1u)) >> 16);
}
// global -> LDS direct DMA, 16B per lane; LDS dest = wave-uniform base + lane*16
__device__ __forceinline__ void gld16(const unsigned short* g, unsigned short* l) {
  __builtin_amdgcn_global_load_lds(
      (const __attribute__((address_space(1))) unsigned int*)g,
      (__attribute__((address_space(3))) unsigned int*)l, 16, 0, 0);
}

// ---------------- prelude: film (2048 blk) + wcvt (512) + per-d tables (512) ----------------
__global__ __launch_bounds__(256) void prelude_kernel(
    const float* __restrict__ emb, const float* __restrict__ Wf,
    const float* __restrict__ bfm, float* __restrict__ film,
    const float* __restrict__ W, unsigned short* __restrict__ Wb,
    const float* __restrict__ A_real, const float* __restrict__ A_imag,
    const float* __restrict__ Cc, const float* __restrict__ log_dt,
    const float* __restrict__ B_ssm, const float* __restrict__ D_skip,
    unsigned short* __restrict__ Pre, unsigned short* __restrict__ Pim,
    unsigned short* __restrict__ Mre, unsigned short* __restrict__ Mim,
    unsigned short* __restrict__ Tt, float* __restrict__ W64r, float* __restrict__ W64i) {
  __shared__ float Ktl[64];
  const int blk = blockIdx.x;
  const int tid = threadIdx.x;
  if (blk < 2048) {            // ---- FiLM
    const int gw = blk * 4 + (tid >> 6);
    const int lane = tid & 63;
    const int b = gw >> 10, j = gw & 1023;
    const float4* ep = (const float4*)(emb + (size_t)b * 512) + lane * 2;
    const float4* wp = (const float4*)(Wf + (size_t)j * 512) + lane * 2;
    float acc = 0.f;
    #pragma unroll
    for (int i = 0; i < 2; i++) {
      const float4 e = ep[i], w = wp[i];
      acc += (e.x / (1.f + __expf(-e.x))) * w.x;
      acc += (e.y / (1.f + __expf(-e.y))) * w.y;
      acc += (e.z / (1.f + __expf(-e.z))) * w.z;
      acc += (e.w / (1.f + __expf(-e.w))) * w.w;
    }
    #pragma unroll
    for (int off = 32; off >= 1; off >>= 1) acc += __shfl_xor(acc, off);
    if (lane == 0) film[(size_t)b * 1024 + j] = acc + bfm[j];
  } else if (blk < 2560) {     // ---- W_out fp32 -> bf16
    const int i = (blk - 2048) * 256 + tid;
    const float4 v = ((const float4*)W)[i];
    uint2 pk;
    pk.x = (unsigned)f2bf(v.x) | ((unsigned)f2bf(v.y) << 16);
    pk.y = (unsigned)f2bf(v.z) | ((unsigned)f2bf(v.w) << 16);
    ((uint2*)Wb)[i] = pk;
  } else {                     // ---- tables for d
    const int d = blk - 2560;
    const float dt = __expf(log_dt[d]);
    const int wv = tid >> 6, n = tid & 63;
    {  // K[tau] = Re(sum_n cdt_n w_n^tau) (+D_skip at tau=0); wave wv: taus wv*16..+15
      const int dn = d * 64 + n;
      const float ar = dt * A_real[dn], ai = dt * A_imag[dn];
      const float bs = B_ssm[dn] * dt;
      const float c0 = Cc[dn * 2] * bs, c1 = Cc[dn * 2 + 1] * bs;
      #pragma unroll
      for (int i = 0; i < 16; i++) {
        const float tau = (float)(wv * 16 + i);
        const float ex = __expf(ar * tau);
        float sn, cs; __sincosf(ai * tau, &sn, &cs);
        float r = ex * (c0 * cs - c1 * sn);
        #pragma unroll
        for (int off = 32; off >= 1; off >>= 1) r += __shfl_xor(r, off);
        if (n == 0) Ktl[wv * 16 + i] = (wv * 16 + i == 0) ? (r + D_skip[d]) : r;
      }
    }
    __syncthreads();
    // P[n][s] = w_n^(63-s)
    for (int g = tid; g < 512; g += 256) {
      const int nn = g >> 3, s0 = (g & 7) * 8;
      const int dn = d * 64 + nn;
      const float ar = dt * A_real[dn], ai = dt * A_imag[dn];
      union { unsigned short s[8]; uint4 u; } pr, pi;
      #pragma unroll
      for (int j = 0; j < 8; j++) {
        const float k = (float)(63 - (s0 + j));
        const float ex = __expf(ar * k);
        float sn, cs; __sincosf(ai * k, &sn, &cs);
        pr.s[j] = f2bf(ex * cs); pi.s[j] = f2bf(ex * sn);
      }
      *(uint4*)(Pre + (size_t)d * 4096 + nn * 64 + s0) = pr.u;
      *(uint4*)(Pim + (size_t)d * 4096 + nn * 64 + s0) = pi.u;
    }
    // M[t][n]: re = Re(cdt_n w_n^(t+1)), im = -Im(...)
    for (int g = tid; g < 512; g += 256) {
      const int t = g >> 3, n0 = (g & 7) * 8;
      union { unsigned short s[8]; uint4 u; } mr, mi;
      #pragma unroll
      for (int j = 0; j < 8; j++) {
        const int dn = d * 64 + n0 + j;
        const float ar = dt * A_real[dn], ai = dt * A_imag[dn];
        const float bs = B_ssm[dn] * dt;
        const float c0 = Cc[dn * 2] * bs, c1 = Cc[dn * 2 + 1] * bs;
        const float k = (float)(t + 1);
        const float ex = __expf(ar * k);
        float sn, cs; __sincosf(ai * k, &sn, &cs);
        mr.s[j] = f2bf(ex * (c0 * cs - c1 * sn));
        mi.s[j] = f2bf(-ex * (c0 * sn + c1 * cs));
      }
      *(uint4*)(Mre + (size_t)d * 4096 + t * 64 + n0) = mr.u;
      *(uint4*)(Mim + (size_t)d * 4096 + t * 64 + n0) = mi.u;
    }
    // T[t][s] = K[t-s] for s<=t
    for (int g = tid; g < 512; g += 256) {
      const int t = g >> 3, s0 = (g & 7) * 8;
      union { unsigned short s[8]; uint4 u; } tv;
      #pragma unroll
      for (int j = 0; j < 8; j++) {
        const int s = s0 + j;
        tv.s[j] = (s <= t) ? f2bf(Ktl[t - s]) : (unsigned short)0;
      }
      *(uint4*)(Tt + (size_t)d * 4096 + t * 64 + s0) = tv.u;
    }
    if (tid < 64) {
      const int dn = d * 64 + tid;
      const float ex = __expf(dt * A_real[dn] * 64.f);
      float sn, cs; __sincosf(dt * A_imag[dn] * 64.f, &sn, &cs);
      W64r[d * 64 + tid] = ex * cs;
      W64i[d * 64 + tid] = ex * sn;
    }
  }
}

// ---------------- fused LayerNorm + transpose: x (16384 x 512) fp32 -> xT bf16 [d][m] ----------------
__global__ __launch_bounds__(256) void lnt_kernel(const float* __restrict__ x,
    const float* __restrict__ gamma, const float* __restrict__ beta,
    unsigned short* __restrict__ xT) {
  __shared__ __align__(16) unsigned short t[16 * 520];
  const int r0 = blockIdx.x * 16;
  const int tid = threadIdx.x, wv = tid >> 6, lane = tid & 63;
  const float4* gp = (const float4*)gamma + lane * 2;
  const float4* bp = (const float4*)beta  + lane * 2;
  const float4 g0 = gp[0], g1 = gp[1], bb0 = bp[0], bb1 = bp[1];
  #pragma unroll
  for (int i = 0; i < 4; i++) {
    const int r = wv * 4 + i;
    const float4* xr = (const float4*)(x + (size_t)(r0 + r) * 512) + lane * 2;
    const float4 v0 = xr[0], v1 = xr[1];
    float s  = v0.x + v0.y + v0.z + v0.w + v1.x + v1.y + v1.z + v1.w;
    float sq = v0.x*v0.x + v0.y*v0.y + v0.z*v0.z + v0.w*v0.w
             + v1.x*v1.x + v1.y*v1.y + v1.z*v1.z + v1.w*v1.w;
    #pragma unroll
    for (int off = 32; off >= 1; off >>= 1) {
      s  += __shfl_xor(s, off);
      sq += __shfl_xor(sq, off);
    }
    const float mu   = s * (1.f / 512.f);
    const float var  = sq * (1.f / 512.f) - mu * mu;
    const float rstd = rsqrtf(var + 1e-5f);
    uint4 pk;
    pk.x = (unsigned)f2bf((v0.x - mu) * rstd * g0.x + bb0.x)
         | ((unsigned)f2bf((v0.y - mu) * rstd * g0.y + bb0.y) << 16);
    pk.y = (unsigned)f2bf((v0.z - mu) * rstd * g0.z + bb0.z)
         | ((unsigned)f2bf((v0.w - mu) * rstd * g0.w + bb0.w) << 16);
    pk.z = (unsigned)f2bf((v1.x - mu) * rstd * g1.x + bb1.x)
         | ((unsigned)f2bf((v1.y - mu) * rstd * g1.y + bb1.y) << 16);
    pk.w = (unsigned)f2bf((v1.z - mu) * rstd * g1.z + bb1.z)
         | ((unsigned)f2bf((v1.w - mu) * rstd * g1.w + bb1.w) << 16);
    *(uint4*)&t[r * 520 + lane * 8] = pk;
  }
  __syncthreads();
  // transpose-out: thread = col-pair p; gather 16 rows, write xT[2p][r0..+15], xT[2p+1][...]
  const int p = tid;
  union { unsigned short s[8]; uint4 u; } a0, a1, b0, b1;
  #pragma unroll
  for (int r = 0; r < 8; r++) {
    const unsigned v = *(const unsigned*)&t[r * 520 + p * 2];
    a0.s[r] = (unsigned short)(v & 0xffffu);
    b0.s[r] = (unsigned short)(v >> 16);
  }
  #pragma unroll
  for (int r = 0; r < 8; r++) {
    const unsigned v = *(const unsigned*)&t[(r + 8) * 520 + p * 2];
    a1.s[r] = (unsigned short)(v & 0xffffu);
    b1.s[r] = (unsigned short)(v >> 16);
  }
  unsigned short* o0 = xT + (size_t)(2 * p) * 16384 + r0;
  *(uint4*)o0 = a0.u; *(uint4*)(o0 + 8) = a1.u;
  unsigned short* o1 = xT + (size_t)(2 * p + 1) * 16384 + r0;
  *(uint4*)o1 = b0.u; *(uint4*)(o1 + 8) = b1.u;
}

// ---------------- generic u16 transpose: in[R][C] -> out[C][R], 64x64 tiles ----------------
__global__ __launch_bounds__(256) void tr_kernel(const unsigned short* __restrict__ in,
    unsigned short* __restrict__ out, int R, int C) {
  __shared__ __align__(16) unsigned short t[64 * 72];
  const int c0 = blockIdx.x * 64, r0 = blockIdx.y * 64;
  const int tid = threadIdx.x;
  #pragma unroll
  for (int i = 0; i < 2; i++) {
    const int idx = tid + i * 256;
    const int r = idx >> 3, q = idx & 7;
    const uint4 v = *(const uint4*)(in + (size_t)(r0 + r) * C + c0 + q * 8);
    *(uint4*)&t[r * 72 + ((q ^ (r >> 3)) * 8)] = v;
  }
  __syncthreads();
  #pragma unroll
  for (int i = 0; i < 2; i++) {
    const int idx = tid + i * 256;
    const int c = idx >> 3, g = idx & 7;
    union { unsigned short s[8]; uint4 u; } pk;
    #pragma unroll
    for (int j = 0; j < 8; j++)
      pk.s[j] = t[(g * 8 + j) * 72 + (((c >> 3) ^ g) * 8) + (c & 7)];
    *(uint4*)(out + (size_t)(c0 + c) * R + r0 + g * 8) = pk.u;
  }
}

// ---------------- chunked SSM v3: block = (d, half of batches); tables staged in LDS ----------------
// 128 j per block (4 waves x 32 j). Tables P/M/T live in padded LDS (pitch 68) shared by
// all 4 waves; carry buffer I overwrites E in place (Eb packed bf16 re|im, pitch 131).
__global__ __launch_bounds__(256, 2) void ssm_kernel(
    const unsigned short* __restrict__ xT,
    const unsigned short* __restrict__ Pre, const unsigned short* __restrict__ Pim,
    const unsigned short* __restrict__ Mre, const unsigned short* __restrict__ Mim,
    const unsigned short* __restrict__ Tt,
    const float* __restrict__ W64r, const float* __restrict__ W64i,
    const float* __restrict__ film, unsigned short* __restrict__ y2) {
  extern __shared__ char smem[];
  unsigned short* Pr = (unsigned short*)smem;                // [64][68]
  unsigned short* Pi = Pr + 64 * 68;
  unsigned short* Mr = Pi + 64 * 68;
  unsigned short* Mi = Mr + 64 * 68;
  unsigned short* Tl = Mi + 64 * 68;
  unsigned int*   Eb = (unsigned int*)(Tl + 64 * 68);        // [64][131] bf16 re|im

  const int bx = blockIdx.x;             // 1024 blocks
  const int d = bx & 511, h = bx >> 9;   // h in {0,1}
  const int tid = threadIdx.x;
  const int wv = tid >> 6, lane = tid & 63;
  const int n15 = lane & 15, quad = lane >> 4;
  const int j0 = wv * 32;                // local j base (128 j per block)
  const int jg0 = h * 128;               // global j base
  const size_t dtab = (size_t)d * 4096;

  // ---- stage tables into LDS (5 x 8KB, pitch 64 -> 68)
  {
    const unsigned short* gt[5] = {Pre + dtab, Pim + dtab, Mre + dtab, Mim + dtab, Tt + dtab};
    unsigned short* lt[5] = {Pr, Pi, Mr, Mi, Tl};
    #pragma unroll
    for (int i = 0; i < 10; i++) {
      const int idx = tid + i * 256;          // 0..2559
      const int tb = idx >> 9, r = (idx >> 3) & 63, g = idx & 7;
      const uint4 v = *(const uint4*)(gt[tb] + r * 64 + g * 8);
      *(uint4*)&lt[tb][r * 68 + g * 8] = v;
    }
  }
  // X fragments (B-operand), reused in phases 1 and 3 (issued before barrier to overlap)
  bf8v Xf[2][2];
  #pragma unroll
  for (int ct = 0; ct < 2; ct++)
    #pragma unroll
    for (int kq = 0; kq < 2; kq++)
      Xf[ct][kq] = *(const bf8v*)(xT + (size_t)d * 16384 +
                                  (jg0 + j0 + ct * 16 + n15) * 64 + kq * 32 + quad * 8);
  __syncthreads();

  // ---- Phase 1: E = P @ X  (E[n][j])
  {
    f4v Er[4][2], Ei[4][2];
    #pragma unroll
    for (int a = 0; a < 4; a++)
      #pragma unroll
      for (int b2 = 0; b2 < 2; b2++) { Er[a][b2] = (f4v){0,0,0,0}; Ei[a][b2] = (f4v){0,0,0,0}; }
    #pragma unroll
    for (int mt = 0; mt < 4; mt++)
      #pragma unroll
      for (int kq = 0; kq < 2; kq++) {
        const bf8v pr = *(const bf8v*)&Pr[(mt * 16 + n15) * 68 + kq * 32 + quad * 8];
        const bf8v pi = *(const bf8v*)&Pi[(mt * 16 + n15) * 68 + kq * 32 + quad * 8];
        #pragma unroll
        for (int ct = 0; ct < 2; ct++) {
          Er[mt][ct] = __builtin_amdgcn_mfma_f32_16x16x32_bf16(pr, Xf[ct][kq], Er[mt][ct], 0, 0, 0);
          Ei[mt][ct] = __builtin_amdgcn_mfma_f32_16x16x32_bf16(pi, Xf[ct][kq], Ei[mt][ct], 0, 0, 0);
        }
      }
    #pragma unroll
    for (int mt = 0; mt < 4; mt++)
      #pragma unroll
      for (int ct = 0; ct < 2; ct++)
        #pragma unroll
        for (int i = 0; i < 4; i++) {
          const int row = mt * 16 + quad * 4 + i;
          const int col = j0 + ct * 16 + n15;
          Eb[row * 131 + col] =
              (unsigned)f2bf(Er[mt][ct][i]) | ((unsigned)f2bf(Ei[mt][ct][i]) << 16);
        }
  }
  __syncthreads();

  // ---- Phase 2: per-(n, batch) 32-step carry prefix, in place (E -> I-entering)
  {
    const int n = lane, bp = wv;               // batch b = h*4 + bp
    const float wre = W64r[d * 64 + n], wim = W64i[d * 64 + n];
    unsigned int* row = &Eb[n * 131 + bp * 32];
    float str = 0.f, sti = 0.f;
    #pragma unroll
    for (int c = 0; c < 32; c++) {
      const unsigned u = row[c];
      row[c] = (unsigned)f2bf(str) | ((unsigned)f2bf(sti) << 16);
      const float er = bf2f((unsigned short)(u & 0xffffu));
      const float ei = bf2f((unsigned short)(u >> 16));
      const float nr = er + wre * str - wim * sti;
      const float ni = ei + wre * sti + wim * str;
      str = nr; sti = ni;
    }
  }
  __syncthreads();

  // ---- Phase 3: Y = T @ X + Mre @ I_re^T + (-Mim) @ I_im^T
  f4v Y[4][2];
  #pragma unroll
  for (int a = 0; a < 4; a++)
    #pragma unroll
    for (int b2 = 0; b2 < 2; b2++) Y[a][b2] = (f4v){0,0,0,0};

  #pragma unroll
  for (int mt = 0; mt < 4; mt++)
    #pragma unroll
    for (int kq = 0; kq < 2; kq++) {
      const bf8v tf = *(const bf8v*)&Tl[(mt * 16 + n15) * 68 + kq * 32 + quad * 8];
      #pragma unroll
      for (int ct = 0; ct < 2; ct++)
        Y[mt][ct] = __builtin_amdgcn_mfma_f32_16x16x32_bf16(tf, Xf[ct][kq], Y[mt][ct], 0, 0, 0);
    }

  #pragma unroll
  for (int kq = 0; kq < 2; kq++) {
    BF8 ir[2], ii[2];
    #pragma unroll
    for (int ct = 0; ct < 2; ct++)
      #pragma unroll
      for (int jj = 0; jj < 8; jj++) {
        const unsigned u = Eb[(kq * 32 + quad * 8 + jj) * 131 + (j0 + ct * 16 + n15)];
        ir[ct].e[jj] = (unsigned short)(u & 0xffffu);
        ii[ct].e[jj] = (unsigned short)(u >> 16);
      }
    #pragma unroll
    for (int mt = 0; mt < 4; mt++) {
      const bf8v mr = *(const bf8v*)&Mr[(mt * 16 + n15) * 68 + kq * 32 + quad * 8];
      const bf8v mi = *(const bf8v*)&Mi[(mt * 16 + n15) * 68 + kq * 32 + quad * 8];
      #pragma unroll
      for (int ct = 0; ct < 2; ct++) {
        Y[mt][ct] = __builtin_amdgcn_mfma_f32_16x16x32_bf16(mr, ir[ct].v, Y[mt][ct], 0, 0, 0);
        Y[mt][ct] = __builtin_amdgcn_mfma_f32_16x16x32_bf16(mi, ii[ct].v, Y[mt][ct], 0, 0, 0);
      }
    }
  }

  // ---- epilogue: FiLM + store y2[d][jglob*64 + t]
  #pragma unroll
  for (int ct = 0; ct < 2; ct++) {
    const int jglob = jg0 + j0 + ct * 16 + n15;
    const int b = jglob >> 5;
    const float scl = 1.f + film[b * 1024 + d];
    const float shf = film[b * 1024 + 512 + d];
    #pragma unroll
    for (int mt = 0; mt < 4; mt++) {
      union { unsigned short s[4]; uint2 u; } pk;
      #pragma unroll
      for (int i = 0; i < 4; i++)
        pk.s[i] = f2bf(fmaf(Y[mt][ct][i], scl, shf));
      *(uint2*)(y2 + (size_t)d * 16384 + jglob * 64 + mt * 16 + quad * 4) = pk.u;
    }
  }
}

// ---------------- out_proj + GLU + residual: 128x128 tile, BK=64, swizzled LDS ----------------
__global__ __launch_bounds__(256, 3) void gemm_kernel(
    const unsigned short* __restrict__ y2n, const unsigned short* __restrict__ Wb,
    const float* __restrict__ bo, const float* __restrict__ x,
    float* __restrict__ out) {
  __shared__ __align__(16) unsigned short Al[128 * 64];
  __shared__ __align__(16) unsigned short Bl[128 * 64];
  const int m0 = blockIdx.x * 128, ct = blockIdx.y;
  const int tid = threadIdx.x;
  const int wv = tid >> 6, lane = tid & 63;
  const int n15 = lane & 15, quad = lane >> 4;
  const int sr = lane >> 3;                       // 0..7 row-in-group
  const int sk = ((lane & 7) ^ sr) * 8;           // swizzled k-offset (conflict-free reads)

  f4v acc[2][8];
  #pragma unroll
  for (int mi = 0; mi < 2; mi++)
    #pragma unroll
    for (int t4 = 0; t4 < 8; t4++) acc[mi][t4] = (f4v){0.f, 0.f, 0.f, 0.f};

  for (int kk = 0; kk < 8; kk++) {
    #pragma unroll
    for (int c = 0; c < 4; c++) {
      const int row = wv * 32 + c * 8 + sr;
      gld16(y2n + (size_t)(m0 + row) * 512 + kk * 64 + sk, Al + wv * 2048 + c * 512);
      const int cg = (row < 64) ? (ct * 64 + row) : (512 + ct * 64 + (row - 64));
      gld16(Wb + (size_t)cg * 512 + kk * 64 + sk, Bl + wv * 2048 + c * 512);
    }
    __syncthreads();
    #pragma unroll
    for (int kq = 0; kq < 2; kq++) {
      const int r0 = wv * 32 + n15;
      const int r1 = r0 + 16;
      const bf8v a0 = *(const bf8v*)&Al[r0 * 64 + (((kq * 4 + quad) ^ (r0 & 7)) * 8)];
      const bf8v a1 = *(const bf8v*)&Al[r1 * 64 + (((kq * 4 + quad) ^ (r1 & 7)) * 8)];
      #pragma unroll
      for (int t4 = 0; t4 < 8; t4++) {
        const int rb = t4 * 16 + n15;
        const bf8v bb = *(const bf8v*)&Bl[rb * 64 + (((kq * 4 + quad) ^ (rb & 7)) * 8)];
        acc[0][t4] = __builtin_amdgcn_mfma_f32_16x16x32_bf16(a0, bb, acc[0][t4], 0, 0, 0);
        acc[1][t4] = __builtin_amdgcn_mfma_f32_16x16x32_bf16(a1, bb, acc[1][t4], 0, 0, 0);
      }
    }
    __syncthreads();
  }
  #pragma unroll
  for (int mi = 0; mi < 2; mi++) {
    const int mrow = m0 + wv * 32 + mi * 16 + quad * 4;
    #pragma unroll
    for (int t4 = 0; t4 < 4; t4++) {
      const int c = ct * 64 + t4 * 16 + n15;
      const float ba = bo[c], bg = bo[512 + c];
      #pragma unroll
      for (int i = 0; i < 4; i++) {
        const size_t off = (size_t)(mrow + i) * 512 + c;
        const float av = acc[mi][t4][i] + ba;
        const float gv = acc[mi][t4 + 4][i] + bg;
        out[off] = x[off] + av * (1.f / (1.f + __expf(-gv)));
      }
    }
  }
}

extern "C" void kernel_launch(void* const* d_in, const int* in_sizes, int n_in,
                              void* d_out, int out_size, void* d_ws, size_t ws_size,
                              hipStream_t stream) {
  const float* x      = (const float*)d_in[0];
  const float* emb    = (const float*)d_in[1];
  const float* A_real = (const float*)d_in[2];
  const float* A_imag = (const float*)d_in[3];
  const float* C      = (const float*)d_in[4];
  const float* log_dt = (const float*)d_in[5];
  const float* B_ssm  = (const float*)d_in[6];
  const float* D_skip = (const float*)d_in[7];
  const float* gamma  = (const float*)d_in[8];
  const float* beta   = (const float*)d_in[9];
  const float* W_out  = (const float*)d_in[10];
  const float* b_out  = (const float*)d_in[11];
  const float* W_film = (const float*)d_in[12];
  const float* b_film = (const float*)d_in[13];
  float* out = (float*)d_out;

  char* ws = (char*)d_ws;
  size_t o = 0;
  float*          film = (float*)(ws + o);          o += 32768;
  unsigned short* xT   = (unsigned short*)(ws + o); o += 16777216;
  unsigned short* Wb   = (unsigned short*)(ws + o); o += 1048576;
  unsigned short* Pre  = (unsigned short*)(ws + o); o += 4194304;
  unsigned short* Pim  = (unsigned short*)(ws + o); o += 4194304;
  unsigned short* Mre  = (unsigned short*)(ws + o); o += 4194304;
  unsigned short* Mim  = (unsigned short*)(ws + o); o += 4194304;
  unsigned short* Tt   = (unsigned short*)(ws + o); o += 4194304;
  float*          W64r = (float*)(ws + o);          o += 131072;
  float*          W64i = (float*)(ws + o);          o += 131072;
  unsigned short* y2   = (unsigned short*)(ws + o); o += 16777216;   // [d][m]
  unsigned short* y2n  = (unsigned short*)(ws + o); o += 16777216;   // [m][d]

  prelude_kernel<<<dim3(3072), dim3(256), 0, stream>>>(
      emb, W_film, b_film, film, W_out, Wb,
      A_real, A_imag, C, log_dt, B_ssm, D_skip,
      Pre, Pim, Mre, Mim, Tt, W64r, W64i);
  lnt_kernel<<<dim3(1024), dim3(256), 0, stream>>>(x, gamma, beta, xT);
  ssm_kernel<<<dim3(1024), dim3(256), 77056, stream>>>(xT, Pre, Pim, Mre, Mim, Tt,
                                                       W64r, W64i, film, y2);
  tr_kernel<<<dim3(256, 8), dim3(256), 0, stream>>>(y2, y2n, 512, 16384);
  gemm_kernel<<<dim3(128, 8), dim3(256), 0, stream>>>(y2n, Wb, b_out, x, out);
}